// Round 1
// baseline (694.864 us; speedup 1.0000x reference)
//
#include <hip/hip_runtime.h>
#include <math.h>

#define N_NODES 50000
#define N_EDGES 800000
#define E2 (N_EDGES + N_NODES)   // edges + self loops = 850000
#define HEADS 5
#define C1 32
#define F1 160                   // HEADS*C1

static constexpr size_t alignup(size_t x){ return (x + 255) & ~size_t(255); }
static constexpr size_t OFF_SCAL  = 0;                                        // 64 floats
static constexpr size_t OFF_DEG   = alignup(OFF_SCAL + 64*4);                 // N ints
static constexpr size_t OFF_OFFS  = alignup(OFF_DEG  + (size_t)N_NODES*4);    // N+1 ints
static constexpr size_t OFF_CUR   = alignup(OFF_OFFS + (size_t)(N_NODES+1)*4);// N ints
static constexpr size_t OFF_CSRC  = alignup(OFF_CUR  + (size_t)N_NODES*4);    // E2 ints
static constexpr size_t OFF_CEA   = alignup(OFF_CSRC + (size_t)E2*4);         // E2 floats
static constexpr size_t OFF_AS1   = alignup(OFF_CEA  + (size_t)E2*4);         // N*H
static constexpr size_t OFF_AD1   = alignup(OFF_AS1  + (size_t)N_NODES*HEADS*4);
static constexpr size_t OFF_H2    = alignup(OFF_AD1  + (size_t)N_NODES*HEADS*4);
static constexpr size_t OFF_AS2   = alignup(OFF_H2   + (size_t)N_NODES*HEADS*4);
static constexpr size_t OFF_AD2   = alignup(OFF_AS2  + (size_t)N_NODES*HEADS*4);
static constexpr size_t OFF_H1    = alignup(OFF_AD2  + (size_t)N_NODES*HEADS*4); // N*160
static constexpr size_t OFF_X2    = alignup(OFF_H1   + (size_t)N_NODES*F1*4);    // N*160
static constexpr size_t OFF_ALPHA = alignup(OFF_X2   + (size_t)N_NODES*F1*4);    // E2*H

// ---------------- mean(edge_attr) ----------------
__global__ void k_mean(const float* __restrict__ ea, float* __restrict__ scal){
  float s = 0.f;
  for (int i = blockIdx.x*blockDim.x + threadIdx.x; i < N_EDGES; i += gridDim.x*blockDim.x)
    s += ea[i];
  #pragma unroll
  for (int m = 1; m < 64; m <<= 1) s += __shfl_xor(s, m, 64);
  __shared__ float sh[4];
  int w = threadIdx.x >> 6, l = threadIdx.x & 63;
  if (l == 0) sh[w] = s;
  __syncthreads();
  if (threadIdx.x == 0){
    float t = 0.f;
    for (int i = 0; i < (int)(blockDim.x >> 6); i++) t += sh[i];
    atomicAdd(scal, t);
  }
}

// scal[0]=sum_ea, scal[1]=mean_ea, scal[2..6]=wedot1[h], scal[7..11]=wedot2[h]
__global__ void k_prep(const float* __restrict__ We1, const float* __restrict__ ae1,
                       const float* __restrict__ We2, const float* __restrict__ ae2,
                       float* __restrict__ scal){
  int t = threadIdx.x;
  if (t == 0) scal[1] = scal[0] / (float)N_EDGES;
  if (t < HEADS){
    float s = 0.f;
    for (int c = 0; c < C1; c++) s += We1[t*C1 + c] * ae1[t*C1 + c];
    scal[2 + t] = s;
    scal[7 + t] = We2[t] * ae2[t];
  }
}

// ---------------- CSR build ----------------
__global__ void k_count(const int* __restrict__ dst, int* __restrict__ deg){
  int e = blockIdx.x*blockDim.x + threadIdx.x;
  if (e >= E2) return;
  int d = (e < N_EDGES) ? dst[e] : (e - N_EDGES);
  atomicAdd(&deg[d], 1);
}

__global__ void k_scan(const int* __restrict__ deg, int* __restrict__ offs, int* __restrict__ cur){
  __shared__ int sp[256];
  int tid = threadIdx.x;
  const int chunk = (N_NODES + 255) / 256;
  int start = tid*chunk, end = min(start + chunk, N_NODES);
  int s = 0;
  for (int i = start; i < end; i++) s += deg[i];
  sp[tid] = s;
  __syncthreads();
  for (int off = 1; off < 256; off <<= 1){
    int v = (tid >= off) ? sp[tid - off] : 0;
    __syncthreads();
    sp[tid] += v;
    __syncthreads();
  }
  int run = (tid > 0) ? sp[tid - 1] : 0;
  for (int i = start; i < end; i++){ offs[i] = run; cur[i] = run; run += deg[i]; }
  if (tid == 255) offs[N_NODES] = sp[255];
}

__global__ void k_scatter(const int* __restrict__ src, const int* __restrict__ dst,
                          const float* __restrict__ ea, const float* __restrict__ scal,
                          int* __restrict__ cur, int* __restrict__ csrc, float* __restrict__ cea){
  int e = blockIdx.x*blockDim.x + threadIdx.x;
  if (e >= E2) return;
  int d, s; float a;
  if (e < N_EDGES){ d = dst[e]; s = src[e]; a = ea[e]; }
  else { d = s = e - N_EDGES; a = scal[1]; }
  int pos = atomicAdd(&cur[d], 1);
  csrc[pos] = s;
  cea[pos]  = a;
}

// ---------------- layer 1: h1 = x@W1, alpha_s1/alpha_d1 ----------------
// 2 nodes per 320-thread block; thread i in [0,160) handles channel i of its node.
__global__ __launch_bounds__(320) void k_h1(const float* __restrict__ x, const float* __restrict__ W1,
                    const float* __restrict__ as1w, const float* __restrict__ ad1w,
                    float* __restrict__ h1, float* __restrict__ as1, float* __restrict__ ad1){
  __shared__ float sW[5*F1];
  for (int k = threadIdx.x; k < 5*F1; k += 320) sW[k] = W1[k];
  __syncthreads();
  int nl = threadIdx.x / F1;
  int i  = threadIdx.x - nl*F1;
  int n  = blockIdx.x*2 + nl;
  float hv = 0.f;
  #pragma unroll
  for (int f = 0; f < 5; f++) hv += x[n*5 + f] * sW[f*F1 + i];
  h1[(size_t)n*F1 + i] = hv;
  float vs = hv * as1w[i], vd = hv * ad1w[i];
  #pragma unroll
  for (int m = 16; m >= 1; m >>= 1){
    vs += __shfl_xor(vs, m, 32);
    vd += __shfl_xor(vd, m, 32);
  }
  if ((i & 31) == 0){
    int h = i >> 5;
    as1[n*HEADS + h] = vs;
    ad1[n*HEADS + h] = vd;
  }
}

// ---------------- segment softmax (both layers) ----------------
// thread per (node, head): 3 sweeps over the node's CSR range.
__global__ void k_soft(const int* __restrict__ offs, const int* __restrict__ csrc,
                       const float* __restrict__ cea,
                       const float* __restrict__ as, const float* __restrict__ ad,
                       const float* __restrict__ scal, int scal_off,
                       float* __restrict__ alpha){
  int t = blockIdx.x*blockDim.x + threadIdx.x;
  if (t >= N_NODES*HEADS) return;
  int n = t / HEADS, h = t - n*HEADS;
  float wd  = scal[scal_off + h];
  float adn = ad[n*HEADS + h];
  int j0 = offs[n], j1 = offs[n + 1];
  float m = -1e30f;
  for (int j = j0; j < j1; j++){
    int s = csrc[j];
    float lg = as[s*HEADS + h] + adn + cea[j]*wd;
    lg = (lg > 0.f) ? lg : 0.2f*lg;
    alpha[(size_t)j*HEADS + h] = lg;
    m = fmaxf(m, lg);
  }
  float den = 0.f;
  for (int j = j0; j < j1; j++){
    float v = expf(alpha[(size_t)j*HEADS + h] - m);
    alpha[(size_t)j*HEADS + h] = v;
    den += v;
  }
  float inv = 1.f / (den + 1e-16f);
  for (int j = j0; j < j1; j++) alpha[(size_t)j*HEADS + h] *= inv;
}

// ---------------- layer 1 aggregate + bias + relu -> x2 ----------------
__global__ __launch_bounds__(320) void k_agg1(const int* __restrict__ offs, const int* __restrict__ csrc,
                      const float* __restrict__ alpha, const float* __restrict__ h1,
                      const float* __restrict__ b1, float* __restrict__ x2){
  int nl = threadIdx.x / F1;
  int i  = threadIdx.x - nl*F1;
  int n  = blockIdx.x*2 + nl;
  int h  = i >> 5;
  int j0 = offs[n], j1 = offs[n + 1];
  float acc = 0.f;
  for (int j = j0; j < j1; j++){
    int s = csrc[j];
    float a = alpha[(size_t)j*HEADS + h];
    acc += a * h1[(size_t)s*F1 + i];
  }
  float v = acc + b1[i];
  x2[(size_t)n*F1 + i] = (v > 0.f) ? v : 0.f;
}

// ---------------- layer 2: h2 = x2@W2 (C=1), alpha_s2/alpha_d2 ----------------
// wave per node; 4 waves per 256-thread block.
__global__ __launch_bounds__(256) void k_h2(const float* __restrict__ x2, const float* __restrict__ W2,
                    const float* __restrict__ asw2, const float* __restrict__ adw2,
                    float* __restrict__ h2, float* __restrict__ as2, float* __restrict__ ad2){
  __shared__ float sW[F1*HEADS];
  for (int k = threadIdx.x; k < F1*HEADS; k += 256) sW[k] = W2[k];
  __syncthreads();
  int w = threadIdx.x >> 6, l = threadIdx.x & 63;
  int n = blockIdx.x*4 + w;
  float acc[HEADS] = {0.f, 0.f, 0.f, 0.f, 0.f};
  for (int k = l; k < F1; k += 64){
    float xv = x2[(size_t)n*F1 + k];
    #pragma unroll
    for (int h = 0; h < HEADS; h++) acc[h] += xv * sW[k*HEADS + h];
  }
  #pragma unroll
  for (int m = 1; m < 64; m <<= 1){
    #pragma unroll
    for (int h = 0; h < HEADS; h++) acc[h] += __shfl_xor(acc[h], m, 64);
  }
  if (l == 0){
    #pragma unroll
    for (int h = 0; h < HEADS; h++){
      h2[n*HEADS + h]  = acc[h];
      as2[n*HEADS + h] = acc[h] * asw2[h];
      ad2[n*HEADS + h] = acc[h] * adw2[h];
    }
  }
}

// ---------------- layer 2 aggregate + mean heads + linear + sigmoid ----------------
__global__ void k_agg2(const int* __restrict__ offs, const int* __restrict__ csrc,
                       const float* __restrict__ alpha, const float* __restrict__ h2,
                       const float* __restrict__ b2, const float* __restrict__ Wlin,
                       float* __restrict__ out){
  int n = blockIdx.x*blockDim.x + threadIdx.x;
  if (n >= N_NODES) return;
  int j0 = offs[n], j1 = offs[n + 1];
  float acc[HEADS] = {0.f, 0.f, 0.f, 0.f, 0.f};
  for (int j = j0; j < j1; j++){
    int s = csrc[j];
    #pragma unroll
    for (int h = 0; h < HEADS; h++)
      acc[h] += alpha[(size_t)j*HEADS + h] * h2[s*HEADS + h];
  }
  float v = (acc[0] + acc[1] + acc[2] + acc[3] + acc[4]) * (1.f/HEADS) + b2[0];
  v *= Wlin[0];
  out[n] = 1.f / (1.f + expf(-v));
}

extern "C" void kernel_launch(void* const* d_in, const int* in_sizes, int n_in,
                              void* d_out, int out_size, void* d_ws, size_t ws_size,
                              hipStream_t stream) {
  const float* x    = (const float*)d_in[0];
  const float* ea   = (const float*)d_in[1];
  const int*   src  = (const int*)d_in[2];
  const int*   dst  = (const int*)d_in[3];
  const float* W1   = (const float*)d_in[4];
  const float* as1w = (const float*)d_in[5];
  const float* ad1w = (const float*)d_in[6];
  const float* We1  = (const float*)d_in[7];
  const float* ae1  = (const float*)d_in[8];
  const float* b1   = (const float*)d_in[9];
  const float* W2   = (const float*)d_in[10];
  const float* as2w = (const float*)d_in[11];
  const float* ad2w = (const float*)d_in[12];
  const float* We2  = (const float*)d_in[13];
  const float* ae2  = (const float*)d_in[14];
  const float* b2   = (const float*)d_in[15];
  const float* Wlin = (const float*)d_in[16];

  char* ws = (char*)d_ws;
  float* scal  = (float*)(ws + OFF_SCAL);
  int*   deg   = (int*)  (ws + OFF_DEG);
  int*   offs  = (int*)  (ws + OFF_OFFS);
  int*   cur   = (int*)  (ws + OFF_CUR);
  int*   csrc  = (int*)  (ws + OFF_CSRC);
  float* cea   = (float*)(ws + OFF_CEA);
  float* as1   = (float*)(ws + OFF_AS1);
  float* ad1   = (float*)(ws + OFF_AD1);
  float* h2b   = (float*)(ws + OFF_H2);
  float* as2   = (float*)(ws + OFF_AS2);
  float* ad2   = (float*)(ws + OFF_AD2);
  float* h1    = (float*)(ws + OFF_H1);
  float* x2    = (float*)(ws + OFF_X2);
  float* alpha = (float*)(ws + OFF_ALPHA);
  float* outp  = (float*)d_out;

  hipMemsetAsync(scal, 0, 64*sizeof(float), stream);
  hipMemsetAsync(deg, 0, N_NODES*sizeof(int), stream);

  k_mean   <<<256, 256, 0, stream>>>(ea, scal);
  k_prep   <<<1, 64, 0, stream>>>(We1, ae1, We2, ae2, scal);
  k_count  <<<(E2 + 255)/256, 256, 0, stream>>>(dst, deg);
  k_scan   <<<1, 256, 0, stream>>>(deg, offs, cur);
  k_scatter<<<(E2 + 255)/256, 256, 0, stream>>>(src, dst, ea, scal, cur, csrc, cea);

  k_h1     <<<N_NODES/2, 320, 0, stream>>>(x, W1, as1w, ad1w, h1, as1, ad1);
  k_soft   <<<(N_NODES*HEADS + 255)/256, 256, 0, stream>>>(offs, csrc, cea, as1, ad1, scal, 2, alpha);
  k_agg1   <<<N_NODES/2, 320, 0, stream>>>(offs, csrc, alpha, h1, b1, x2);

  k_h2     <<<N_NODES/4, 256, 0, stream>>>(x2, W2, as2w, ad2w, h2b, as2, ad2);
  k_soft   <<<(N_NODES*HEADS + 255)/256, 256, 0, stream>>>(offs, csrc, cea, as2, ad2, scal, 7, alpha);
  k_agg2   <<<(N_NODES + 255)/256, 256, 0, stream>>>(offs, csrc, alpha, h2b, b2, Wlin, outp);
}

// Round 2
// 555.066 us; speedup vs baseline: 1.2519x; 1.2519x over previous
//
#include <hip/hip_runtime.h>
#include <math.h>

#define N_NODES 50000
#define N_EDGES 800000
#define E2 (N_EDGES + N_NODES)   // 850000
#define HEADS 5
#define C1 32
#define F1 160
#define NB 196                   // ceil(N_NODES/256)

static constexpr size_t alignup(size_t x){ return (x + 255) & ~size_t(255); }
static constexpr size_t OFF_SCAL  = 0;                                          // 64 floats
static constexpr size_t OFF_DEG   = alignup(OFF_SCAL + 64*4);                   // N ints
static constexpr size_t OFF_OFFS  = alignup(OFF_DEG  + (size_t)N_NODES*4);      // N+1 ints
static constexpr size_t OFF_CUR   = alignup(OFF_OFFS + (size_t)(N_NODES+1)*4);  // N ints
static constexpr size_t OFF_BSUM  = alignup(OFF_CUR  + (size_t)N_NODES*4);      // 256 ints
static constexpr size_t OFF_BPREF = alignup(OFF_BSUM + 256*4);                  // 256 ints
static constexpr size_t OFF_CSRC  = alignup(OFF_BPREF+ 256*4);                  // E2 ints
static constexpr size_t OFF_CEA   = alignup(OFF_CSRC + (size_t)E2*4);           // E2 floats
static constexpr size_t OFF_AS1   = alignup(OFF_CEA  + (size_t)E2*4);           // N*H
static constexpr size_t OFF_AD1   = alignup(OFF_AS1  + (size_t)N_NODES*HEADS*4);
static constexpr size_t OFF_H2P   = alignup(OFF_AD1  + (size_t)N_NODES*HEADS*4); // N*8 padded
static constexpr size_t OFF_AS2P  = alignup(OFF_H2P  + (size_t)N_NODES*8*4);
static constexpr size_t OFF_AD2P  = alignup(OFF_AS2P + (size_t)N_NODES*8*4);
static constexpr size_t OFF_H1    = alignup(OFF_AD2P + (size_t)N_NODES*8*4);     // N*160
static constexpr size_t OFF_X2    = alignup(OFF_H1   + (size_t)N_NODES*F1*4);    // N*160

__device__ __forceinline__ void online_upd(float lg, float v, float& m, float& den, float& acc){
  float nm = fmaxf(m, lg);
  float sc = __expf(m - nm);
  float p  = __expf(lg - nm);
  den = den*sc + p;
  acc = acc*sc + p*v;
  m = nm;
}

// ---- pass over edges: deg histogram + sum(edge_attr) ----
__global__ void k_pre(const float* __restrict__ ea, const int* __restrict__ dst,
                      int* __restrict__ deg, float* __restrict__ scal){
  int e = blockIdx.x*blockDim.x + threadIdx.x;
  float s = 0.f;
  if (e < N_EDGES) s = ea[e];
  if (e < E2){
    int d = (e < N_EDGES) ? dst[e] : (e - N_EDGES);
    atomicAdd(&deg[d], 1);
  }
  #pragma unroll
  for (int m = 1; m < 64; m <<= 1) s += __shfl_xor(s, m, 64);
  if ((threadIdx.x & 63) == 0 && s != 0.f) atomicAdd(scal, s);
}

// scal[0]=sum_ea, scal[1]=mean_ea, scal[2..6]=wedot1[h], scal[7..11]=wedot2[h]
__global__ void k_prep(const float* __restrict__ We1, const float* __restrict__ ae1,
                       const float* __restrict__ We2, const float* __restrict__ ae2,
                       float* __restrict__ scal){
  int t = threadIdx.x;
  if (t == 0) scal[1] = scal[0] / (float)N_EDGES;
  if (t < HEADS){
    float s = 0.f;
    for (int c = 0; c < C1; c++) s += We1[t*C1 + c] * ae1[t*C1 + c];
    scal[2 + t] = s;
    scal[7 + t] = We2[t] * ae2[t];
  }
}

// ---- CSR scan: block sums -> scan of sums -> per-block offsets ----
__global__ void k_bsum(const int* __restrict__ deg, int* __restrict__ bsum){
  int i = blockIdx.x*256 + threadIdx.x;
  int d = (i < N_NODES) ? deg[i] : 0;
  #pragma unroll
  for (int m = 1; m < 64; m <<= 1) d += __shfl_xor(d, m, 64);
  __shared__ int sh[4];
  if ((threadIdx.x & 63) == 0) sh[threadIdx.x >> 6] = d;
  __syncthreads();
  if (threadIdx.x == 0) bsum[blockIdx.x] = sh[0] + sh[1] + sh[2] + sh[3];
}

__global__ void k_bscan(const int* __restrict__ bsum, int* __restrict__ bpref){
  __shared__ int sp[256];
  int t = threadIdx.x;
  int v = (t < NB) ? bsum[t] : 0;
  sp[t] = v;
  __syncthreads();
  for (int off = 1; off < 256; off <<= 1){
    int u = (t >= off) ? sp[t - off] : 0;
    __syncthreads();
    sp[t] += u;
    __syncthreads();
  }
  if (t < NB) bpref[t] = sp[t] - v;   // exclusive
}

__global__ void k_offs(const int* __restrict__ deg, const int* __restrict__ bpref,
                       int* __restrict__ offs, int* __restrict__ cur){
  __shared__ int sp[256];
  int b = blockIdx.x, t = threadIdx.x;
  int i = b*256 + t;
  int d = (i < N_NODES) ? deg[i] : 0;
  sp[t] = d;
  __syncthreads();
  for (int off = 1; off < 256; off <<= 1){
    int u = (t >= off) ? sp[t - off] : 0;
    __syncthreads();
    sp[t] += u;
    __syncthreads();
  }
  int val = bpref[b] + sp[t] - d;     // exclusive global prefix
  if (i < N_NODES){ offs[i] = val; cur[i] = val; }
  if (i == N_NODES) offs[N_NODES] = E2;
}

__global__ void k_scatter(const int* __restrict__ src, const int* __restrict__ dst,
                          const float* __restrict__ ea, const float* __restrict__ scal,
                          int* __restrict__ cur, int* __restrict__ csrc, float* __restrict__ cea){
  int e = blockIdx.x*blockDim.x + threadIdx.x;
  if (e >= E2) return;
  int d, s; float a;
  if (e < N_EDGES){ d = dst[e]; s = src[e]; a = ea[e]; }
  else { d = s = e - N_EDGES; a = scal[1]; }
  int pos = atomicAdd(&cur[d], 1);
  csrc[pos] = s;
  cea[pos]  = a;
}

// ---- layer 1: h1 = x@W1, alpha_s1/alpha_d1 ----
__global__ __launch_bounds__(320) void k_h1(const float* __restrict__ x, const float* __restrict__ W1,
                    const float* __restrict__ as1w, const float* __restrict__ ad1w,
                    float* __restrict__ h1, float* __restrict__ as1, float* __restrict__ ad1){
  __shared__ float sW[5*F1];
  for (int k = threadIdx.x; k < 5*F1; k += 320) sW[k] = W1[k];
  __syncthreads();
  int nl = threadIdx.x / F1;
  int i  = threadIdx.x - nl*F1;
  int n  = blockIdx.x*2 + nl;
  float hv = 0.f;
  #pragma unroll
  for (int f = 0; f < 5; f++) hv += x[n*5 + f] * sW[f*F1 + i];
  h1[(size_t)n*F1 + i] = hv;
  float vs = hv * as1w[i], vd = hv * ad1w[i];
  #pragma unroll
  for (int m = 16; m >= 1; m >>= 1){
    vs += __shfl_xor(vs, m, 32);
    vd += __shfl_xor(vd, m, 32);
  }
  if ((i & 31) == 0){
    int h = i >> 5;
    as1[n*HEADS + h] = vs;
    ad1[n*HEADS + h] = vd;
  }
}

// ---- layer 1: fused online-softmax aggregate + bias + relu -> x2 ----
__global__ __launch_bounds__(320) void k_agg1(const int* __restrict__ offs, const int* __restrict__ csrc,
                      const float* __restrict__ cea,
                      const float* __restrict__ as1, const float* __restrict__ ad1,
                      const float* __restrict__ scal,
                      const float* __restrict__ h1,
                      const float* __restrict__ b1, float* __restrict__ x2){
  int nl = threadIdx.x / F1;
  int i  = threadIdx.x - nl*F1;
  int n  = blockIdx.x*2 + nl;
  int h  = i >> 5;
  float wd  = scal[2 + h];
  float adn = ad1[n*HEADS + h];
  int j0 = offs[n], j1 = offs[n + 1];
  float m = -1e30f, den = 0.f, acc = 0.f;
  int j = j0;
  for (; j + 3 < j1; j += 4){
    int s0 = csrc[j], s1 = csrc[j+1], s2 = csrc[j+2], s3 = csrc[j+3];
    float c0 = cea[j], c1 = cea[j+1], c2 = cea[j+2], c3 = cea[j+3];
    float g0 = as1[s0*HEADS + h], g1 = as1[s1*HEADS + h];
    float g2 = as1[s2*HEADS + h], g3 = as1[s3*HEADS + h];
    float v0 = h1[(size_t)s0*F1 + i], v1 = h1[(size_t)s1*F1 + i];
    float v2 = h1[(size_t)s2*F1 + i], v3 = h1[(size_t)s3*F1 + i];
    float l0 = g0 + adn + c0*wd; l0 = fmaxf(l0, 0.2f*l0);
    float l1g = g1 + adn + c1*wd; l1g = fmaxf(l1g, 0.2f*l1g);
    float l2 = g2 + adn + c2*wd; l2 = fmaxf(l2, 0.2f*l2);
    float l3 = g3 + adn + c3*wd; l3 = fmaxf(l3, 0.2f*l3);
    online_upd(l0, v0, m, den, acc);
    online_upd(l1g, v1, m, den, acc);
    online_upd(l2, v2, m, den, acc);
    online_upd(l3, v3, m, den, acc);
  }
  for (; j < j1; ++j){
    int s = csrc[j];
    float g = as1[s*HEADS + h];
    float v = h1[(size_t)s*F1 + i];
    float lg = g + adn + cea[j]*wd; lg = fmaxf(lg, 0.2f*lg);
    online_upd(lg, v, m, den, acc);
  }
  float v = acc / (den + 1e-16f) + b1[i];
  x2[(size_t)n*F1 + i] = (v > 0.f) ? v : 0.f;
}

// ---- layer 2: h2 = x2@W2 (C=1), padded rows of 8 for float4 gathers ----
__global__ __launch_bounds__(256) void k_h2(const float* __restrict__ x2, const float* __restrict__ W2,
                    const float* __restrict__ scal,   // unused slots ok
                    const float* __restrict__ asw2, const float* __restrict__ adw2,
                    float* __restrict__ h2p, float* __restrict__ as2p, float* __restrict__ ad2p){
  __shared__ float sW[F1*HEADS];
  for (int k = threadIdx.x; k < F1*HEADS; k += 256) sW[k] = W2[k];
  __syncthreads();
  int w = threadIdx.x >> 6, l = threadIdx.x & 63;
  int n = blockIdx.x*4 + w;
  float acc[HEADS] = {0.f, 0.f, 0.f, 0.f, 0.f};
  for (int k = l; k < F1; k += 64){
    float xv = x2[(size_t)n*F1 + k];
    #pragma unroll
    for (int h = 0; h < HEADS; h++) acc[h] += xv * sW[k*HEADS + h];
  }
  #pragma unroll
  for (int m = 1; m < 64; m <<= 1){
    #pragma unroll
    for (int h = 0; h < HEADS; h++) acc[h] += __shfl_xor(acc[h], m, 64);
  }
  if (l == 0){
    #pragma unroll
    for (int h = 0; h < HEADS; h++){
      h2p[n*8 + h]  = acc[h];
      as2p[n*8 + h] = acc[h] * asw2[h];
      ad2p[n*8 + h] = acc[h] * adw2[h];
    }
    // zero pad slots so float4 loads see clean data
    for (int h = HEADS; h < 8; h++){ h2p[n*8+h] = 0.f; as2p[n*8+h] = 0.f; ad2p[n*8+h] = 0.f; }
  }
}

// ---- layer 2: wave-per-node fused softmax aggregate + mean + linear + sigmoid ----
__global__ __launch_bounds__(256) void k_agg2(const int* __restrict__ offs, const int* __restrict__ csrc,
                      const float* __restrict__ cea,
                      const float* __restrict__ as2p, const float* __restrict__ ad2p,
                      const float* __restrict__ h2p, const float* __restrict__ scal,
                      const float* __restrict__ b2, const float* __restrict__ Wlin,
                      float* __restrict__ out){
  int w = threadIdx.x >> 6, l = threadIdx.x & 63;
  int n = blockIdx.x*4 + w;
  const float4* as4 = (const float4*)as2p;
  const float4* h24 = (const float4*)h2p;
  float4 ada = ((const float4*)ad2p)[2*n];
  float adb = ad2p[n*8 + 4];
  float adn[HEADS] = {ada.x, ada.y, ada.z, ada.w, adb};
  float wd[HEADS];
  #pragma unroll
  for (int h = 0; h < HEADS; h++) wd[h] = scal[7 + h];
  int j0 = offs[n], j1 = offs[n + 1];

  // pass 1: max logits per head
  float mh[HEADS] = {-1e30f,-1e30f,-1e30f,-1e30f,-1e30f};
  for (int j = j0 + l; j < j1; j += 64){
    int s = csrc[j];
    float c = cea[j];
    float4 ga = as4[2*s];
    float gb4 = as2p[s*8 + 4];
    float g[HEADS] = {ga.x, ga.y, ga.z, ga.w, gb4};
    #pragma unroll
    for (int h = 0; h < HEADS; h++){
      float lg = g[h] + adn[h] + c*wd[h];
      lg = fmaxf(lg, 0.2f*lg);
      mh[h] = fmaxf(mh[h], lg);
    }
  }
  #pragma unroll
  for (int m = 1; m < 64; m <<= 1){
    #pragma unroll
    for (int h = 0; h < HEADS; h++) mh[h] = fmaxf(mh[h], __shfl_xor(mh[h], m, 64));
  }

  // pass 2: den + weighted accumulate
  float den[HEADS] = {0,0,0,0,0};
  float ac[HEADS]  = {0,0,0,0,0};
  for (int j = j0 + l; j < j1; j += 64){
    int s = csrc[j];
    float c = cea[j];
    float4 ga = as4[2*s];
    float gb4 = as2p[s*8 + 4];
    float g[HEADS] = {ga.x, ga.y, ga.z, ga.w, gb4};
    float4 ha = h24[2*s];
    float hb4 = h2p[s*8 + 4];
    float hv[HEADS] = {ha.x, ha.y, ha.z, ha.w, hb4};
    #pragma unroll
    for (int h = 0; h < HEADS; h++){
      float lg = g[h] + adn[h] + c*wd[h];
      lg = fmaxf(lg, 0.2f*lg);
      float p = __expf(lg - mh[h]);
      den[h] += p;
      ac[h]  += p * hv[h];
    }
  }
  #pragma unroll
  for (int m = 1; m < 64; m <<= 1){
    #pragma unroll
    for (int h = 0; h < HEADS; h++){
      den[h] += __shfl_xor(den[h], m, 64);
      ac[h]  += __shfl_xor(ac[h], m, 64);
    }
  }
  if (l == 0){
    float v = 0.f;
    #pragma unroll
    for (int h = 0; h < HEADS; h++) v += ac[h] / (den[h] + 1e-16f);
    v = v * (1.f/HEADS) + b2[0];
    v *= Wlin[0];
    out[n] = 1.f / (1.f + __expf(-v));
  }
}

extern "C" void kernel_launch(void* const* d_in, const int* in_sizes, int n_in,
                              void* d_out, int out_size, void* d_ws, size_t ws_size,
                              hipStream_t stream) {
  const float* x    = (const float*)d_in[0];
  const float* ea   = (const float*)d_in[1];
  const int*   src  = (const int*)d_in[2];
  const int*   dst  = (const int*)d_in[3];
  const float* W1   = (const float*)d_in[4];
  const float* as1w = (const float*)d_in[5];
  const float* ad1w = (const float*)d_in[6];
  const float* We1  = (const float*)d_in[7];
  const float* ae1  = (const float*)d_in[8];
  const float* b1   = (const float*)d_in[9];
  const float* W2   = (const float*)d_in[10];
  const float* as2w = (const float*)d_in[11];
  const float* ad2w = (const float*)d_in[12];
  const float* We2  = (const float*)d_in[13];
  const float* ae2  = (const float*)d_in[14];
  const float* b2   = (const float*)d_in[15];
  const float* Wlin = (const float*)d_in[16];

  char* ws = (char*)d_ws;
  float* scal  = (float*)(ws + OFF_SCAL);
  int*   deg   = (int*)  (ws + OFF_DEG);
  int*   offs  = (int*)  (ws + OFF_OFFS);
  int*   cur   = (int*)  (ws + OFF_CUR);
  int*   bsum  = (int*)  (ws + OFF_BSUM);
  int*   bpref = (int*)  (ws + OFF_BPREF);
  int*   csrc  = (int*)  (ws + OFF_CSRC);
  float* cea   = (float*)(ws + OFF_CEA);
  float* as1   = (float*)(ws + OFF_AS1);
  float* ad1   = (float*)(ws + OFF_AD1);
  float* h2p   = (float*)(ws + OFF_H2P);
  float* as2p  = (float*)(ws + OFF_AS2P);
  float* ad2p  = (float*)(ws + OFF_AD2P);
  float* h1    = (float*)(ws + OFF_H1);
  float* x2    = (float*)(ws + OFF_X2);
  float* outp  = (float*)d_out;

  hipMemsetAsync(ws, 0, OFF_OFFS, stream);   // zeros scal + deg

  k_pre    <<<(E2 + 255)/256, 256, 0, stream>>>(ea, dst, deg, scal);
  k_prep   <<<1, 64, 0, stream>>>(We1, ae1, We2, ae2, scal);
  k_bsum   <<<NB, 256, 0, stream>>>(deg, bsum);
  k_bscan  <<<1, 256, 0, stream>>>(bsum, bpref);
  k_offs   <<<NB, 256, 0, stream>>>(deg, bpref, offs, cur);
  k_scatter<<<(E2 + 255)/256, 256, 0, stream>>>(src, dst, ea, scal, cur, csrc, cea);

  k_h1     <<<N_NODES/2, 320, 0, stream>>>(x, W1, as1w, ad1w, h1, as1, ad1);
  k_agg1   <<<N_NODES/2, 320, 0, stream>>>(offs, csrc, cea, as1, ad1, scal, h1, b1, x2);

  k_h2     <<<N_NODES/4, 256, 0, stream>>>(x2, W2, scal, as2w, ad2w, h2p, as2p, ad2p);
  k_agg2   <<<N_NODES/4, 256, 0, stream>>>(offs, csrc, cea, as2p, ad2p, h2p, scal, b2, Wlin, outp);
}

// Round 3
// 387.541 us; speedup vs baseline: 1.7930x; 1.4323x over previous
//
#include <hip/hip_runtime.h>
#include <math.h>

#define N_NODES 50000
#define N_EDGES 800000
#define E2 (N_EDGES + N_NODES)   // 850000
#define HEADS 5
#define C1 32
#define F1 160

// counting-sort CSR build
#define NBK 391                  // buckets of 128 nodes: 391*128 = 50048
#define NBL 416                  // edge-chunk blocks
#define CH  2044                 // 416*2044 = 850304 >= E2
#define MTOT (NBK*NBL)           // 162656
#define MC  636                  // ceil(MTOT/256)

static constexpr size_t alignup(size_t x){ return (x + 255) & ~size_t(255); }
static constexpr size_t OFF_SCAL  = 0;                                           // 64 floats
static constexpr size_t OFF_H     = alignup(OFF_SCAL + 64*4);                    // MTOT ints
static constexpr size_t OFF_PART  = alignup(OFF_H    + (size_t)MTOT*4);          // MC ints
static constexpr size_t OFF_PPREF = alignup(OFF_PART + (size_t)MC*4);            // MC ints
static constexpr size_t OFF_BST   = alignup(OFF_PPREF+ (size_t)MC*4);            // NBK+1 ints
static constexpr size_t OFF_OFFS  = alignup(OFF_BST  + (size_t)(NBK+1)*4);       // N+1 ints
static constexpr size_t OFF_BSRC  = alignup(OFF_OFFS + (size_t)(N_NODES+1)*4);   // E2 ints
static constexpr size_t OFF_BEA   = alignup(OFF_BSRC + (size_t)E2*4);            // E2 floats
static constexpr size_t OFF_BLOC  = alignup(OFF_BEA  + (size_t)E2*4);            // E2 ints
static constexpr size_t OFF_CSRC  = alignup(OFF_BLOC + (size_t)E2*4);            // E2 ints
static constexpr size_t OFF_CEA   = alignup(OFF_CSRC + (size_t)E2*4);            // E2 floats
static constexpr size_t OFF_AS1   = alignup(OFF_CEA  + (size_t)E2*4);            // N*H
static constexpr size_t OFF_AD1   = alignup(OFF_AS1  + (size_t)N_NODES*HEADS*4);
static constexpr size_t OFF_H2P   = alignup(OFF_AD1  + (size_t)N_NODES*HEADS*4); // N*8
static constexpr size_t OFF_AS2P  = alignup(OFF_H2P  + (size_t)N_NODES*8*4);
static constexpr size_t OFF_AD2P  = alignup(OFF_AS2P + (size_t)N_NODES*8*4);
static constexpr size_t OFF_H1    = alignup(OFF_AD2P + (size_t)N_NODES*8*4);     // N*160
static constexpr size_t OFF_X2    = alignup(OFF_H1   + (size_t)N_NODES*F1*4);    // N*160

__device__ __forceinline__ void online_upd(float lg, float v, float& m, float& den, float& acc){
  float nm = fmaxf(m, lg);
  float sc = __expf(m - nm);
  float p  = __expf(lg - nm);
  den = den*sc + p;
  acc = acc*sc + p*v;
  m = nm;
}

// ---- pass 1: LDS coarse histogram + ea sum ----
__global__ __launch_bounds__(256) void k_hist(const int* __restrict__ dst, const float* __restrict__ ea,
                       int* __restrict__ H, float* __restrict__ scal){
  __shared__ int hist[NBK];
  for (int k = threadIdx.x; k < NBK; k += 256) hist[k] = 0;
  __syncthreads();
  int b = blockIdx.x;
  int e0 = b*CH, e1 = min(e0 + CH, E2);
  float s = 0.f;
  for (int e = e0 + threadIdx.x; e < e1; e += 256){
    int d;
    if (e < N_EDGES){ d = dst[e]; s += ea[e]; }
    else d = e - N_EDGES;
    atomicAdd(&hist[d >> 7], 1);
  }
  __syncthreads();
  for (int k = threadIdx.x; k < NBK; k += 256) H[(size_t)k*NBL + b] = hist[k];
  #pragma unroll
  for (int m = 1; m < 64; m <<= 1) s += __shfl_xor(s, m, 64);
  if ((threadIdx.x & 63) == 0) atomicAdd(scal, s);
}

// scal[0]=sum_ea, scal[1]=mean_ea, scal[2..6]=wedot1[h], scal[7..11]=wedot2[h]
__global__ void k_prep(const float* __restrict__ We1, const float* __restrict__ ae1,
                       const float* __restrict__ We2, const float* __restrict__ ae2,
                       float* __restrict__ scal){
  int t = threadIdx.x;
  if (t == 0) scal[1] = scal[0] / (float)N_EDGES;
  if (t < HEADS){
    float s = 0.f;
    for (int c = 0; c < C1; c++) s += We1[t*C1 + c] * ae1[t*C1 + c];
    scal[2 + t] = s;
    scal[7 + t] = We2[t] * ae2[t];
  }
}

// ---- scan of H (MTOT entries) ----
__global__ void k_s1(const int* __restrict__ H, int* __restrict__ partial){
  int i = blockIdx.x*256 + threadIdx.x;
  int v = (i < MTOT) ? H[i] : 0;
  #pragma unroll
  for (int m = 1; m < 64; m <<= 1) v += __shfl_xor(v, m, 64);
  __shared__ int sh[4];
  if ((threadIdx.x & 63) == 0) sh[threadIdx.x >> 6] = v;
  __syncthreads();
  if (threadIdx.x == 0) partial[blockIdx.x] = sh[0] + sh[1] + sh[2] + sh[3];
}

__global__ __launch_bounds__(1024) void k_s2(const int* __restrict__ partial, int* __restrict__ ppref,
                      int* __restrict__ offs, int* __restrict__ bstart){
  __shared__ int sp[1024];
  int t = threadIdx.x;
  int v = (t < MC) ? partial[t] : 0;
  sp[t] = v;
  __syncthreads();
  for (int off = 1; off < 1024; off <<= 1){
    int u = (t >= off) ? sp[t - off] : 0;
    __syncthreads();
    sp[t] += u;
    __syncthreads();
  }
  if (t < MC) ppref[t] = sp[t] - v;
  if (t == 0){ offs[N_NODES] = E2; bstart[NBK] = E2; }
}

__global__ void k_s3(int* __restrict__ H, const int* __restrict__ ppref, int* __restrict__ bstart){
  __shared__ int sp[256];
  int b = blockIdx.x, t = threadIdx.x;
  int i = b*256 + t;
  int v = (i < MTOT) ? H[i] : 0;
  sp[t] = v;
  __syncthreads();
  for (int off = 1; off < 256; off <<= 1){
    int u = (t >= off) ? sp[t - off] : 0;
    __syncthreads();
    sp[t] += u;
    __syncthreads();
  }
  int P = ppref[b] + sp[t] - v;  // exclusive global prefix
  if (i < MTOT){
    H[i] = P;
    if (i % NBL == 0) bstart[i / NBL] = P;
  }
}

// ---- pass 2: scatter into bucket-major intermediates (LDS atomics only) ----
__global__ __launch_bounds__(256) void k_scat(const int* __restrict__ src, const int* __restrict__ dst,
                       const float* __restrict__ ea, const float* __restrict__ scal,
                       const int* __restrict__ H,
                       int* __restrict__ bsrc, float* __restrict__ bea, int* __restrict__ bloc){
  __shared__ int lofs[NBK];
  int b = blockIdx.x;
  for (int k = threadIdx.x; k < NBK; k += 256) lofs[k] = H[(size_t)k*NBL + b];
  __syncthreads();
  float mean = scal[1];
  int e0 = b*CH, e1 = min(e0 + CH, E2);
  for (int e = e0 + threadIdx.x; e < e1; e += 256){
    int d, s; float a;
    if (e < N_EDGES){ d = dst[e]; s = src[e]; a = ea[e]; }
    else { d = s = e - N_EDGES; a = mean; }
    int pos = atomicAdd(&lofs[d >> 7], 1);
    bsrc[pos] = s;
    bea[pos]  = a;
    bloc[pos] = d & 127;
  }
}

// ---- pass 3: per-bucket fine sort -> offs, csrc, cea ----
__global__ __launch_bounds__(256) void k_final(const int* __restrict__ bstart,
                        const int* __restrict__ bsrc, const float* __restrict__ bea,
                        const int* __restrict__ bloc,
                        int* __restrict__ offs, int* __restrict__ csrc, float* __restrict__ cea){
  int k = blockIdx.x, t = threadIdx.x;
  int r0 = bstart[k], r1 = bstart[k + 1];
  __shared__ int cnt[128], pfx[128], cur[128];
  if (t < 128) cnt[t] = 0;
  __syncthreads();
  for (int j = r0 + t; j < r1; j += 256) atomicAdd(&cnt[bloc[j]], 1);
  __syncthreads();
  if (t == 0){
    int run = 0;
    for (int i = 0; i < 128; i++){ pfx[i] = run; cur[i] = run; run += cnt[i]; }
  }
  __syncthreads();
  int n = k*128 + t;
  if (t < 128 && n < N_NODES) offs[n] = r0 + pfx[t];
  for (int j = r0 + t; j < r1; j += 256){
    int pos = r0 + atomicAdd(&cur[bloc[j]], 1);
    csrc[pos] = bsrc[j];
    cea[pos]  = bea[j];
  }
}

// ---- layer 1: h1 = x@W1, alpha_s1/alpha_d1 ----
__global__ __launch_bounds__(320) void k_h1(const float* __restrict__ x, const float* __restrict__ W1,
                    const float* __restrict__ as1w, const float* __restrict__ ad1w,
                    float* __restrict__ h1, float* __restrict__ as1, float* __restrict__ ad1){
  __shared__ float sW[5*F1];
  for (int k = threadIdx.x; k < 5*F1; k += 320) sW[k] = W1[k];
  __syncthreads();
  int nl = threadIdx.x / F1;
  int i  = threadIdx.x - nl*F1;
  int n  = blockIdx.x*2 + nl;
  float hv = 0.f;
  #pragma unroll
  for (int f = 0; f < 5; f++) hv += x[n*5 + f] * sW[f*F1 + i];
  h1[(size_t)n*F1 + i] = hv;
  float vs = hv * as1w[i], vd = hv * ad1w[i];
  #pragma unroll
  for (int m = 16; m >= 1; m >>= 1){
    vs += __shfl_xor(vs, m, 32);
    vd += __shfl_xor(vd, m, 32);
  }
  if ((i & 31) == 0){
    int h = i >> 5;
    as1[n*HEADS + h] = vs;
    ad1[n*HEADS + h] = vd;
  }
}

// ---- layer 1: fused online-softmax aggregate + bias + relu -> x2 ----
__global__ __launch_bounds__(320) void k_agg1(const int* __restrict__ offs, const int* __restrict__ csrc,
                      const float* __restrict__ cea,
                      const float* __restrict__ as1, const float* __restrict__ ad1,
                      const float* __restrict__ scal,
                      const float* __restrict__ h1,
                      const float* __restrict__ b1, float* __restrict__ x2){
  int nl = threadIdx.x / F1;
  int i  = threadIdx.x - nl*F1;
  int n  = blockIdx.x*2 + nl;
  int h  = i >> 5;
  float wd  = scal[2 + h];
  float adn = ad1[n*HEADS + h];
  int j0 = offs[n], j1 = offs[n + 1];
  float m = -1e30f, den = 0.f, acc = 0.f;
  int j = j0;
  for (; j + 3 < j1; j += 4){
    int s0 = csrc[j], s1 = csrc[j+1], s2 = csrc[j+2], s3 = csrc[j+3];
    float c0 = cea[j], c1 = cea[j+1], c2 = cea[j+2], c3 = cea[j+3];
    float g0 = as1[s0*HEADS + h], g1 = as1[s1*HEADS + h];
    float g2 = as1[s2*HEADS + h], g3 = as1[s3*HEADS + h];
    float v0 = h1[(size_t)s0*F1 + i], v1 = h1[(size_t)s1*F1 + i];
    float v2 = h1[(size_t)s2*F1 + i], v3 = h1[(size_t)s3*F1 + i];
    float l0 = g0 + adn + c0*wd; l0 = fmaxf(l0, 0.2f*l0);
    float l1g = g1 + adn + c1*wd; l1g = fmaxf(l1g, 0.2f*l1g);
    float l2 = g2 + adn + c2*wd; l2 = fmaxf(l2, 0.2f*l2);
    float l3 = g3 + adn + c3*wd; l3 = fmaxf(l3, 0.2f*l3);
    online_upd(l0, v0, m, den, acc);
    online_upd(l1g, v1, m, den, acc);
    online_upd(l2, v2, m, den, acc);
    online_upd(l3, v3, m, den, acc);
  }
  for (; j < j1; ++j){
    int s = csrc[j];
    float g = as1[s*HEADS + h];
    float v = h1[(size_t)s*F1 + i];
    float lg = g + adn + cea[j]*wd; lg = fmaxf(lg, 0.2f*lg);
    online_upd(lg, v, m, den, acc);
  }
  float v = acc / (den + 1e-16f) + b1[i];
  x2[(size_t)n*F1 + i] = (v > 0.f) ? v : 0.f;
}

// ---- layer 2: h2 = x2@W2 (C=1), padded rows of 8 ----
__global__ __launch_bounds__(256) void k_h2(const float* __restrict__ x2, const float* __restrict__ W2,
                    const float* __restrict__ asw2, const float* __restrict__ adw2,
                    float* __restrict__ h2p, float* __restrict__ as2p, float* __restrict__ ad2p){
  __shared__ float sW[F1*HEADS];
  for (int k = threadIdx.x; k < F1*HEADS; k += 256) sW[k] = W2[k];
  __syncthreads();
  int w = threadIdx.x >> 6, l = threadIdx.x & 63;
  int n = blockIdx.x*4 + w;
  float acc[HEADS] = {0.f, 0.f, 0.f, 0.f, 0.f};
  for (int k = l; k < F1; k += 64){
    float xv = x2[(size_t)n*F1 + k];
    #pragma unroll
    for (int h = 0; h < HEADS; h++) acc[h] += xv * sW[k*HEADS + h];
  }
  #pragma unroll
  for (int m = 1; m < 64; m <<= 1){
    #pragma unroll
    for (int h = 0; h < HEADS; h++) acc[h] += __shfl_xor(acc[h], m, 64);
  }
  if (l == 0){
    #pragma unroll
    for (int h = 0; h < HEADS; h++){
      h2p[n*8 + h]  = acc[h];
      as2p[n*8 + h] = acc[h] * asw2[h];
      ad2p[n*8 + h] = acc[h] * adw2[h];
    }
    for (int h = HEADS; h < 8; h++){ h2p[n*8+h] = 0.f; as2p[n*8+h] = 0.f; ad2p[n*8+h] = 0.f; }
  }
}

// ---- layer 2: wave-per-node fused softmax aggregate + mean + linear + sigmoid ----
__global__ __launch_bounds__(256) void k_agg2(const int* __restrict__ offs, const int* __restrict__ csrc,
                      const float* __restrict__ cea,
                      const float* __restrict__ as2p, const float* __restrict__ ad2p,
                      const float* __restrict__ h2p, const float* __restrict__ scal,
                      const float* __restrict__ b2, const float* __restrict__ Wlin,
                      float* __restrict__ out){
  int w = threadIdx.x >> 6, l = threadIdx.x & 63;
  int n = blockIdx.x*4 + w;
  const float4* as4 = (const float4*)as2p;
  const float4* h24 = (const float4*)h2p;
  float4 ada = ((const float4*)ad2p)[2*n];
  float adb = ad2p[n*8 + 4];
  float adn[HEADS] = {ada.x, ada.y, ada.z, ada.w, adb};
  float wd[HEADS];
  #pragma unroll
  for (int h = 0; h < HEADS; h++) wd[h] = scal[7 + h];
  int j0 = offs[n], j1 = offs[n + 1];

  float mh[HEADS] = {-1e30f,-1e30f,-1e30f,-1e30f,-1e30f};
  for (int j = j0 + l; j < j1; j += 64){
    int s = csrc[j];
    float c = cea[j];
    float4 ga = as4[2*s];
    float gb4 = as2p[s*8 + 4];
    float g[HEADS] = {ga.x, ga.y, ga.z, ga.w, gb4};
    #pragma unroll
    for (int h = 0; h < HEADS; h++){
      float lg = g[h] + adn[h] + c*wd[h];
      lg = fmaxf(lg, 0.2f*lg);
      mh[h] = fmaxf(mh[h], lg);
    }
  }
  #pragma unroll
  for (int m = 1; m < 64; m <<= 1){
    #pragma unroll
    for (int h = 0; h < HEADS; h++) mh[h] = fmaxf(mh[h], __shfl_xor(mh[h], m, 64));
  }

  float den[HEADS] = {0,0,0,0,0};
  float ac[HEADS]  = {0,0,0,0,0};
  for (int j = j0 + l; j < j1; j += 64){
    int s = csrc[j];
    float c = cea[j];
    float4 ga = as4[2*s];
    float gb4 = as2p[s*8 + 4];
    float g[HEADS] = {ga.x, ga.y, ga.z, ga.w, gb4};
    float4 ha = h24[2*s];
    float hb4 = h2p[s*8 + 4];
    float hv[HEADS] = {ha.x, ha.y, ha.z, ha.w, hb4};
    #pragma unroll
    for (int h = 0; h < HEADS; h++){
      float lg = g[h] + adn[h] + c*wd[h];
      lg = fmaxf(lg, 0.2f*lg);
      float p = __expf(lg - mh[h]);
      den[h] += p;
      ac[h]  += p * hv[h];
    }
  }
  #pragma unroll
  for (int m = 1; m < 64; m <<= 1){
    #pragma unroll
    for (int h = 0; h < HEADS; h++){
      den[h] += __shfl_xor(den[h], m, 64);
      ac[h]  += __shfl_xor(ac[h], m, 64);
    }
  }
  if (l == 0){
    float v = 0.f;
    #pragma unroll
    for (int h = 0; h < HEADS; h++) v += ac[h] / (den[h] + 1e-16f);
    v = v * (1.f/HEADS) + b2[0];
    v *= Wlin[0];
    out[n] = 1.f / (1.f + __expf(-v));
  }
}

extern "C" void kernel_launch(void* const* d_in, const int* in_sizes, int n_in,
                              void* d_out, int out_size, void* d_ws, size_t ws_size,
                              hipStream_t stream) {
  const float* x    = (const float*)d_in[0];
  const float* ea   = (const float*)d_in[1];
  const int*   src  = (const int*)d_in[2];
  const int*   dst  = (const int*)d_in[3];
  const float* W1   = (const float*)d_in[4];
  const float* as1w = (const float*)d_in[5];
  const float* ad1w = (const float*)d_in[6];
  const float* We1  = (const float*)d_in[7];
  const float* ae1  = (const float*)d_in[8];
  const float* b1   = (const float*)d_in[9];
  const float* W2   = (const float*)d_in[10];
  const float* as2w = (const float*)d_in[11];
  const float* ad2w = (const float*)d_in[12];
  const float* We2  = (const float*)d_in[13];
  const float* ae2  = (const float*)d_in[14];
  const float* b2   = (const float*)d_in[15];
  const float* Wlin = (const float*)d_in[16];

  char* ws = (char*)d_ws;
  float* scal   = (float*)(ws + OFF_SCAL);
  int*   H      = (int*)  (ws + OFF_H);
  int*   part   = (int*)  (ws + OFF_PART);
  int*   ppref  = (int*)  (ws + OFF_PPREF);
  int*   bstart = (int*)  (ws + OFF_BST);
  int*   offs   = (int*)  (ws + OFF_OFFS);
  int*   bsrc   = (int*)  (ws + OFF_BSRC);
  float* bea    = (float*)(ws + OFF_BEA);
  int*   bloc   = (int*)  (ws + OFF_BLOC);
  int*   csrc   = (int*)  (ws + OFF_CSRC);
  float* cea    = (float*)(ws + OFF_CEA);
  float* as1    = (float*)(ws + OFF_AS1);
  float* ad1    = (float*)(ws + OFF_AD1);
  float* h2p    = (float*)(ws + OFF_H2P);
  float* as2p   = (float*)(ws + OFF_AS2P);
  float* ad2p   = (float*)(ws + OFF_AD2P);
  float* h1     = (float*)(ws + OFF_H1);
  float* x2     = (float*)(ws + OFF_X2);
  float* outp   = (float*)d_out;

  hipMemsetAsync(scal, 0, 64*sizeof(float), stream);

  k_hist  <<<NBL, 256, 0, stream>>>(dst, ea, H, scal);
  k_prep  <<<1, 64, 0, stream>>>(We1, ae1, We2, ae2, scal);
  k_s1    <<<MC, 256, 0, stream>>>(H, part);
  k_s2    <<<1, 1024, 0, stream>>>(part, ppref, offs, bstart);
  k_s3    <<<MC, 256, 0, stream>>>(H, ppref, bstart);
  k_scat  <<<NBL, 256, 0, stream>>>(src, dst, ea, scal, H, bsrc, bea, bloc);
  k_final <<<NBK, 256, 0, stream>>>(bstart, bsrc, bea, bloc, offs, csrc, cea);

  k_h1    <<<N_NODES/2, 320, 0, stream>>>(x, W1, as1w, ad1w, h1, as1, ad1);
  k_agg1  <<<N_NODES/2, 320, 0, stream>>>(offs, csrc, cea, as1, ad1, scal, h1, b1, x2);

  k_h2    <<<N_NODES/4, 256, 0, stream>>>(x2, W2, as2w, ad2w, h2p, as2p, ad2p);
  k_agg2  <<<N_NODES/4, 256, 0, stream>>>(offs, csrc, cea, as2p, ad2p, h2p, scal, b2, Wlin, outp);
}

// Round 4
// 363.572 us; speedup vs baseline: 1.9112x; 1.0659x over previous
//
#include <hip/hip_runtime.h>
#include <hip/hip_fp16.h>
#include <math.h>

#define N_NODES 50000
#define N_EDGES 800000
#define E2 (N_EDGES + N_NODES)   // 850000
#define HEADS 5
#define C1 32
#define F1 160

// counting-sort CSR build
#define NBK 391                  // buckets of 128 nodes
#define NBL 416                  // edge-chunk blocks
#define CH  2044                 // 416*2044 >= E2
#define MTOT (NBK*NBL)           // 162656
#define MC  636                  // ceil(MTOT/256)

static constexpr size_t alignup(size_t x){ return (x + 255) & ~size_t(255); }
static constexpr size_t OFF_SCAL  = 0;                                           // 64 f
static constexpr size_t OFF_H     = alignup(OFF_SCAL + 64*4);                    // MTOT i
static constexpr size_t OFF_PART  = alignup(OFF_H    + (size_t)MTOT*4);
static constexpr size_t OFF_PPREF = alignup(OFF_PART + (size_t)MC*4);
static constexpr size_t OFF_BST   = alignup(OFF_PPREF+ (size_t)MC*4);            // NBK+1
static constexpr size_t OFF_OFFS  = alignup(OFF_BST  + (size_t)(NBK+1)*4);       // N+1
static constexpr size_t OFF_BSRC  = alignup(OFF_OFFS + (size_t)(N_NODES+1)*4);   // E2 i
static constexpr size_t OFF_BEA   = alignup(OFF_BSRC + (size_t)E2*4);            // E2 f
static constexpr size_t OFF_BLOC  = alignup(OFF_BEA  + (size_t)E2*4);            // E2 i
static constexpr size_t OFF_CSRC  = alignup(OFF_BLOC + (size_t)E2*4);            // E2 i
static constexpr size_t OFF_CEA   = alignup(OFF_CSRC + (size_t)E2*4);            // E2 f
static constexpr size_t OFF_AS1P  = alignup(OFF_CEA  + (size_t)E2*4);            // N*8 f
static constexpr size_t OFF_AD1P  = alignup(OFF_AS1P + (size_t)N_NODES*8*4);
static constexpr size_t OFF_IDEN1 = alignup(OFF_AD1P + (size_t)N_NODES*8*4);
static constexpr size_t OFF_H2P   = alignup(OFF_IDEN1+ (size_t)N_NODES*8*4);
static constexpr size_t OFF_AS2P  = alignup(OFF_H2P  + (size_t)N_NODES*8*4);
static constexpr size_t OFF_AD2P  = alignup(OFF_AS2P + (size_t)N_NODES*8*4);
static constexpr size_t OFF_H1H   = alignup(OFF_AD2P + (size_t)N_NODES*8*4);     // N*160 half
static constexpr size_t OFF_X2H   = alignup(OFF_H1H  + (size_t)N_NODES*F1*2);    // N*160 half
static constexpr size_t OFF_ALPH  = alignup(OFF_X2H  + (size_t)N_NODES*F1*2);    // 5*E2 f

// ---- pass 1: LDS coarse histogram + ea sum ----
__global__ __launch_bounds__(256) void k_hist(const int* __restrict__ dst, const float* __restrict__ ea,
                       int* __restrict__ H, float* __restrict__ scal){
  __shared__ int hist[NBK];
  for (int k = threadIdx.x; k < NBK; k += 256) hist[k] = 0;
  __syncthreads();
  int b = blockIdx.x;
  int e0 = b*CH, e1 = min(e0 + CH, E2);
  float s = 0.f;
  for (int e = e0 + threadIdx.x; e < e1; e += 256){
    int d;
    if (e < N_EDGES){ d = dst[e]; s += ea[e]; }
    else d = e - N_EDGES;
    atomicAdd(&hist[d >> 7], 1);
  }
  __syncthreads();
  for (int k = threadIdx.x; k < NBK; k += 256) H[(size_t)k*NBL + b] = hist[k];
  #pragma unroll
  for (int m = 1; m < 64; m <<= 1) s += __shfl_xor(s, m, 64);
  if ((threadIdx.x & 63) == 0) atomicAdd(scal, s);
}

// scal[0]=sum_ea, scal[1]=mean_ea, scal[2..6]=wedot1[h], scal[7..11]=wedot2[h]
__global__ void k_prep(const float* __restrict__ We1, const float* __restrict__ ae1,
                       const float* __restrict__ We2, const float* __restrict__ ae2,
                       float* __restrict__ scal){
  int t = threadIdx.x;
  if (t == 0) scal[1] = scal[0] / (float)N_EDGES;
  if (t < HEADS){
    float s = 0.f;
    for (int c = 0; c < C1; c++) s += We1[t*C1 + c] * ae1[t*C1 + c];
    scal[2 + t] = s;
    scal[7 + t] = We2[t] * ae2[t];
  }
}

// ---- scan of H ----
__global__ void k_s1(const int* __restrict__ H, int* __restrict__ partial){
  int i = blockIdx.x*256 + threadIdx.x;
  int v = (i < MTOT) ? H[i] : 0;
  #pragma unroll
  for (int m = 1; m < 64; m <<= 1) v += __shfl_xor(v, m, 64);
  __shared__ int sh[4];
  if ((threadIdx.x & 63) == 0) sh[threadIdx.x >> 6] = v;
  __syncthreads();
  if (threadIdx.x == 0) partial[blockIdx.x] = sh[0] + sh[1] + sh[2] + sh[3];
}

__global__ __launch_bounds__(1024) void k_s2(const int* __restrict__ partial, int* __restrict__ ppref,
                      int* __restrict__ offs, int* __restrict__ bstart){
  __shared__ int sp[1024];
  int t = threadIdx.x;
  int v = (t < MC) ? partial[t] : 0;
  sp[t] = v;
  __syncthreads();
  for (int off = 1; off < 1024; off <<= 1){
    int u = (t >= off) ? sp[t - off] : 0;
    __syncthreads();
    sp[t] += u;
    __syncthreads();
  }
  if (t < MC) ppref[t] = sp[t] - v;
  if (t == 0){ offs[N_NODES] = E2; bstart[NBK] = E2; }
}

__global__ void k_s3(int* __restrict__ H, const int* __restrict__ ppref, int* __restrict__ bstart){
  __shared__ int sp[256];
  int b = blockIdx.x, t = threadIdx.x;
  int i = b*256 + t;
  int v = (i < MTOT) ? H[i] : 0;
  sp[t] = v;
  __syncthreads();
  for (int off = 1; off < 256; off <<= 1){
    int u = (t >= off) ? sp[t - off] : 0;
    __syncthreads();
    sp[t] += u;
    __syncthreads();
  }
  int P = ppref[b] + sp[t] - v;
  if (i < MTOT){
    H[i] = P;
    if (i % NBL == 0) bstart[i / NBL] = P;
  }
}

// ---- pass 2: scatter into bucket-major intermediates ----
__global__ __launch_bounds__(256) void k_scat(const int* __restrict__ src, const int* __restrict__ dst,
                       const float* __restrict__ ea, const float* __restrict__ scal,
                       const int* __restrict__ H,
                       int* __restrict__ bsrc, float* __restrict__ bea, int* __restrict__ bloc){
  __shared__ int lofs[NBK];
  int b = blockIdx.x;
  for (int k = threadIdx.x; k < NBK; k += 256) lofs[k] = H[(size_t)k*NBL + b];
  __syncthreads();
  float mean = scal[1];
  int e0 = b*CH, e1 = min(e0 + CH, E2);
  for (int e = e0 + threadIdx.x; e < e1; e += 256){
    int d, s; float a;
    if (e < N_EDGES){ d = dst[e]; s = src[e]; a = ea[e]; }
    else { d = s = e - N_EDGES; a = mean; }
    int pos = atomicAdd(&lofs[d >> 7], 1);
    bsrc[pos] = s;
    bea[pos]  = a;
    bloc[pos] = d & 127;
  }
}

// ---- pass 3: per-bucket fine sort ----
__global__ __launch_bounds__(256) void k_final(const int* __restrict__ bstart,
                        const int* __restrict__ bsrc, const float* __restrict__ bea,
                        const int* __restrict__ bloc,
                        int* __restrict__ offs, int* __restrict__ csrc, float* __restrict__ cea){
  int k = blockIdx.x, t = threadIdx.x;
  int r0 = bstart[k], r1 = bstart[k + 1];
  __shared__ int cnt[128], pfx[128], cur[128];
  if (t < 128) cnt[t] = 0;
  __syncthreads();
  for (int j = r0 + t; j < r1; j += 256) atomicAdd(&cnt[bloc[j]], 1);
  __syncthreads();
  if (t == 0){
    int run = 0;
    for (int i = 0; i < 128; i++){ pfx[i] = run; cur[i] = run; run += cnt[i]; }
  }
  __syncthreads();
  int n = k*128 + t;
  if (t < 128 && n < N_NODES) offs[n] = r0 + pfx[t];
  for (int j = r0 + t; j < r1; j += 256){
    int pos = r0 + atomicAdd(&cur[bloc[j]], 1);
    csrc[pos] = bsrc[j];
    cea[pos]  = bea[j];
  }
}

// ---- layer 1: h1h(fp16) = x@W1, as1p/ad1p (padded 8) ----
// 4 nodes x 80 threads; thread c handles channels 2c,2c+1.
__global__ __launch_bounds__(320) void k_h1(const float* __restrict__ x, const float* __restrict__ W1,
                    const float* __restrict__ as1w, const float* __restrict__ ad1w,
                    __half* __restrict__ h1h, float* __restrict__ as1p, float* __restrict__ ad1p){
  __shared__ float sW[5*F1];
  for (int k = threadIdx.x; k < 5*F1; k += 320) sW[k] = W1[k];
  __syncthreads();
  int nl = threadIdx.x / 80;
  int c  = threadIdx.x - nl*80;
  int n  = blockIdx.x*4 + nl;
  int c0 = 2*c;
  float hv0 = 0.f, hv1 = 0.f;
  #pragma unroll
  for (int f = 0; f < 5; f++){
    float xv = x[n*5 + f];
    hv0 += xv * sW[f*F1 + c0];
    hv1 += xv * sW[f*F1 + c0 + 1];
  }
  ((__half2*)h1h)[n*80 + c] = __floats2half2_rn(hv0, hv1);
  float vs = hv0*as1w[c0] + hv1*as1w[c0+1];
  float vd = hv0*ad1w[c0] + hv1*ad1w[c0+1];
  #pragma unroll
  for (int m = 8; m >= 1; m >>= 1){
    vs += __shfl_xor(vs, m, 64);
    vd += __shfl_xor(vd, m, 64);
  }
  if ((c & 15) == 0){
    int h = c >> 4;
    as1p[n*8 + h] = vs;
    ad1p[n*8 + h] = vd;
  }
}

// ---- layer 1 softmax stats: alpha (SoA, unnormalized) + 1/den ----
__global__ __launch_bounds__(256) void k_soft2(const int* __restrict__ offs, const int* __restrict__ csrc,
                        const float* __restrict__ cea,
                        const float* __restrict__ as1p, const float* __restrict__ ad1p,
                        const float* __restrict__ scal,
                        float* __restrict__ alpha, float* __restrict__ iden1){
  int w = threadIdx.x >> 6, l = threadIdx.x & 63;
  int n = blockIdx.x*4 + w;
  float wd[HEADS], adn[HEADS];
  #pragma unroll
  for (int h = 0; h < HEADS; h++){ wd[h] = scal[2 + h]; adn[h] = ad1p[n*8 + h]; }
  int j0 = offs[n], j1 = offs[n + 1];

  float mh[HEADS] = {-1e30f,-1e30f,-1e30f,-1e30f,-1e30f};
  for (int j = j0 + l; j < j1; j += 64){
    int s = csrc[j];
    float c = cea[j];
    float4 g4 = *(const float4*)(as1p + s*8);
    float g5 = as1p[s*8 + 4];
    float g[HEADS] = {g4.x, g4.y, g4.z, g4.w, g5};
    #pragma unroll
    for (int h = 0; h < HEADS; h++){
      float lg = g[h] + adn[h] + c*wd[h];
      lg = fmaxf(lg, 0.2f*lg);
      mh[h] = fmaxf(mh[h], lg);
    }
  }
  #pragma unroll
  for (int m = 1; m < 64; m <<= 1){
    #pragma unroll
    for (int h = 0; h < HEADS; h++) mh[h] = fmaxf(mh[h], __shfl_xor(mh[h], m, 64));
  }

  float den[HEADS] = {0,0,0,0,0};
  for (int j = j0 + l; j < j1; j += 64){
    int s = csrc[j];
    float c = cea[j];
    float4 g4 = *(const float4*)(as1p + s*8);
    float g5 = as1p[s*8 + 4];
    float g[HEADS] = {g4.x, g4.y, g4.z, g4.w, g5};
    #pragma unroll
    for (int h = 0; h < HEADS; h++){
      float lg = g[h] + adn[h] + c*wd[h];
      lg = fmaxf(lg, 0.2f*lg);
      float p = __expf(lg - mh[h]);
      den[h] += p;
      alpha[(size_t)h*E2 + j] = p;
    }
  }
  #pragma unroll
  for (int m = 1; m < 64; m <<= 1){
    #pragma unroll
    for (int h = 0; h < HEADS; h++) den[h] += __shfl_xor(den[h], m, 64);
  }
  if (l == 0){
    #pragma unroll
    for (int h = 0; h < HEADS; h++) iden1[n*8 + h] = 1.f / (den[h] + 1e-16f);
  }
}

// ---- layer 1 aggregate: pure FMA gather -> x2h(fp16) ----
// 4 nodes x 80 threads; thread c: channels 2c,2c+1, head c>>4.
__global__ __launch_bounds__(320) void k_agg1(const int* __restrict__ offs, const int* __restrict__ csrc,
                      const float* __restrict__ alpha, const float* __restrict__ iden1,
                      const __half* __restrict__ h1h,
                      const float* __restrict__ b1, __half* __restrict__ x2h){
  int nl = threadIdx.x / 80;
  int c  = threadIdx.x - nl*80;
  int n  = blockIdx.x*4 + nl;
  int h  = c >> 4;
  const float* aph = alpha + (size_t)h*E2;
  const __half2* h12 = (const __half2*)h1h;
  int j0 = offs[n], j1 = offs[n + 1];
  float acc0 = 0.f, acc1 = 0.f;
  int j = j0;
  int jal = min(j1, (j0 + 3) & ~3);
  for (; j < jal; ++j){
    int s = csrc[j];
    float a = aph[j];
    float2 f = __half22float2(h12[(size_t)s*80 + c]);
    acc0 += a*f.x; acc1 += a*f.y;
  }
  for (; j + 3 < j1; j += 4){
    int4   ss = *(const int4*)(csrc + j);
    float4 aa = *(const float4*)(aph + j);
    float2 f0 = __half22float2(h12[(size_t)ss.x*80 + c]);
    float2 f1 = __half22float2(h12[(size_t)ss.y*80 + c]);
    float2 f2 = __half22float2(h12[(size_t)ss.z*80 + c]);
    float2 f3 = __half22float2(h12[(size_t)ss.w*80 + c]);
    acc0 += aa.x*f0.x; acc1 += aa.x*f0.y;
    acc0 += aa.y*f1.x; acc1 += aa.y*f1.y;
    acc0 += aa.z*f2.x; acc1 += aa.z*f2.y;
    acc0 += aa.w*f3.x; acc1 += aa.w*f3.y;
  }
  for (; j < j1; ++j){
    int s = csrc[j];
    float a = aph[j];
    float2 f = __half22float2(h12[(size_t)s*80 + c]);
    acc0 += a*f.x; acc1 += a*f.y;
  }
  float inv = iden1[n*8 + h];
  float v0 = acc0*inv + b1[2*c];
  float v1 = acc1*inv + b1[2*c + 1];
  v0 = (v0 > 0.f) ? v0 : 0.f;
  v1 = (v1 > 0.f) ? v1 : 0.f;
  ((__half2*)x2h)[n*80 + c] = __floats2half2_rn(v0, v1);
}

// ---- layer 2: h2 = x2h@W2, padded rows of 8 ----
__global__ __launch_bounds__(256) void k_h2(const __half* __restrict__ x2h, const float* __restrict__ W2,
                    const float* __restrict__ asw2, const float* __restrict__ adw2,
                    float* __restrict__ h2p, float* __restrict__ as2p, float* __restrict__ ad2p){
  __shared__ float sW[F1*HEADS];
  for (int k = threadIdx.x; k < F1*HEADS; k += 256) sW[k] = W2[k];
  __syncthreads();
  int w = threadIdx.x >> 6, l = threadIdx.x & 63;
  int n = blockIdx.x*4 + w;
  const __half2* x22 = (const __half2*)x2h;
  float acc[HEADS] = {0.f, 0.f, 0.f, 0.f, 0.f};
  for (int k2 = l; k2 < 80; k2 += 64){
    float2 f = __half22float2(x22[n*80 + k2]);
    #pragma unroll
    for (int h = 0; h < HEADS; h++)
      acc[h] += f.x * sW[(2*k2)*HEADS + h] + f.y * sW[(2*k2+1)*HEADS + h];
  }
  #pragma unroll
  for (int m = 1; m < 64; m <<= 1){
    #pragma unroll
    for (int h = 0; h < HEADS; h++) acc[h] += __shfl_xor(acc[h], m, 64);
  }
  if (l == 0){
    #pragma unroll
    for (int h = 0; h < HEADS; h++){
      h2p[n*8 + h]  = acc[h];
      as2p[n*8 + h] = acc[h] * asw2[h];
      ad2p[n*8 + h] = acc[h] * adw2[h];
    }
  }
}

// ---- layer 2: wave-per-node fused softmax aggregate + mean + linear + sigmoid ----
__global__ __launch_bounds__(256) void k_agg2(const int* __restrict__ offs, const int* __restrict__ csrc,
                      const float* __restrict__ cea,
                      const float* __restrict__ as2p, const float* __restrict__ ad2p,
                      const float* __restrict__ h2p, const float* __restrict__ scal,
                      const float* __restrict__ b2, const float* __restrict__ Wlin,
                      float* __restrict__ out){
  int w = threadIdx.x >> 6, l = threadIdx.x & 63;
  int n = blockIdx.x*4 + w;
  float adn[HEADS], wd[HEADS];
  #pragma unroll
  for (int h = 0; h < HEADS; h++){ adn[h] = ad2p[n*8 + h]; wd[h] = scal[7 + h]; }
  int j0 = offs[n], j1 = offs[n + 1];

  float mh[HEADS] = {-1e30f,-1e30f,-1e30f,-1e30f,-1e30f};
  for (int j = j0 + l; j < j1; j += 64){
    int s = csrc[j];
    float c = cea[j];
    float4 g4 = *(const float4*)(as2p + s*8);
    float g5 = as2p[s*8 + 4];
    float g[HEADS] = {g4.x, g4.y, g4.z, g4.w, g5};
    #pragma unroll
    for (int h = 0; h < HEADS; h++){
      float lg = g[h] + adn[h] + c*wd[h];
      lg = fmaxf(lg, 0.2f*lg);
      mh[h] = fmaxf(mh[h], lg);
    }
  }
  #pragma unroll
  for (int m = 1; m < 64; m <<= 1){
    #pragma unroll
    for (int h = 0; h < HEADS; h++) mh[h] = fmaxf(mh[h], __shfl_xor(mh[h], m, 64));
  }

  float den[HEADS] = {0,0,0,0,0};
  float ac[HEADS]  = {0,0,0,0,0};
  for (int j = j0 + l; j < j1; j += 64){
    int s = csrc[j];
    float c = cea[j];
    float4 g4 = *(const float4*)(as2p + s*8);
    float g5 = as2p[s*8 + 4];
    float g[HEADS] = {g4.x, g4.y, g4.z, g4.w, g5};
    float4 h4 = *(const float4*)(h2p + s*8);
    float h5 = h2p[s*8 + 4];
    float hv[HEADS] = {h4.x, h4.y, h4.z, h4.w, h5};
    #pragma unroll
    for (int h = 0; h < HEADS; h++){
      float lg = g[h] + adn[h] + c*wd[h];
      lg = fmaxf(lg, 0.2f*lg);
      float p = __expf(lg - mh[h]);
      den[h] += p;
      ac[h]  += p * hv[h];
    }
  }
  #pragma unroll
  for (int m = 1; m < 64; m <<= 1){
    #pragma unroll
    for (int h = 0; h < HEADS; h++){
      den[h] += __shfl_xor(den[h], m, 64);
      ac[h]  += __shfl_xor(ac[h], m, 64);
    }
  }
  if (l == 0){
    float v = 0.f;
    #pragma unroll
    for (int h = 0; h < HEADS; h++) v += ac[h] / (den[h] + 1e-16f);
    v = v * (1.f/HEADS) + b2[0];
    v *= Wlin[0];
    out[n] = 1.f / (1.f + __expf(-v));
  }
}

extern "C" void kernel_launch(void* const* d_in, const int* in_sizes, int n_in,
                              void* d_out, int out_size, void* d_ws, size_t ws_size,
                              hipStream_t stream) {
  const float* x    = (const float*)d_in[0];
  const float* ea   = (const float*)d_in[1];
  const int*   src  = (const int*)d_in[2];
  const int*   dst  = (const int*)d_in[3];
  const float* W1   = (const float*)d_in[4];
  const float* as1w = (const float*)d_in[5];
  const float* ad1w = (const float*)d_in[6];
  const float* We1  = (const float*)d_in[7];
  const float* ae1  = (const float*)d_in[8];
  const float* b1   = (const float*)d_in[9];
  const float* W2   = (const float*)d_in[10];
  const float* as2w = (const float*)d_in[11];
  const float* ad2w = (const float*)d_in[12];
  const float* We2  = (const float*)d_in[13];
  const float* ae2  = (const float*)d_in[14];
  const float* b2   = (const float*)d_in[15];
  const float* Wlin = (const float*)d_in[16];

  char* ws = (char*)d_ws;
  float* scal   = (float*)(ws + OFF_SCAL);
  int*   H      = (int*)  (ws + OFF_H);
  int*   part   = (int*)  (ws + OFF_PART);
  int*   ppref  = (int*)  (ws + OFF_PPREF);
  int*   bstart = (int*)  (ws + OFF_BST);
  int*   offs   = (int*)  (ws + OFF_OFFS);
  int*   bsrc   = (int*)  (ws + OFF_BSRC);
  float* bea    = (float*)(ws + OFF_BEA);
  int*   bloc   = (int*)  (ws + OFF_BLOC);
  int*   csrc   = (int*)  (ws + OFF_CSRC);
  float* cea    = (float*)(ws + OFF_CEA);
  float* as1p   = (float*)(ws + OFF_AS1P);
  float* ad1p   = (float*)(ws + OFF_AD1P);
  float* iden1  = (float*)(ws + OFF_IDEN1);
  float* h2p    = (float*)(ws + OFF_H2P);
  float* as2p   = (float*)(ws + OFF_AS2P);
  float* ad2p   = (float*)(ws + OFF_AD2P);
  __half* h1h   = (__half*)(ws + OFF_H1H);
  __half* x2h   = (__half*)(ws + OFF_X2H);
  float* alpha  = (float*)(ws + OFF_ALPH);
  float* outp   = (float*)d_out;

  hipMemsetAsync(scal, 0, 64*sizeof(float), stream);

  k_hist  <<<NBL, 256, 0, stream>>>(dst, ea, H, scal);
  k_prep  <<<1, 64, 0, stream>>>(We1, ae1, We2, ae2, scal);
  k_s1    <<<MC, 256, 0, stream>>>(H, part);
  k_s2    <<<1, 1024, 0, stream>>>(part, ppref, offs, bstart);
  k_s3    <<<MC, 256, 0, stream>>>(H, ppref, bstart);
  k_scat  <<<NBL, 256, 0, stream>>>(src, dst, ea, scal, H, bsrc, bea, bloc);
  k_final <<<NBK, 256, 0, stream>>>(bstart, bsrc, bea, bloc, offs, csrc, cea);

  k_h1    <<<N_NODES/4, 320, 0, stream>>>(x, W1, as1w, ad1w, h1h, as1p, ad1p);
  k_soft2 <<<N_NODES/4, 256, 0, stream>>>(offs, csrc, cea, as1p, ad1p, scal, alpha, iden1);
  k_agg1  <<<N_NODES/4, 320, 0, stream>>>(offs, csrc, alpha, iden1, h1h, b1, x2h);

  k_h2    <<<N_NODES/4, 256, 0, stream>>>(x2h, W2, as2w, ad2w, h2p, as2p, ad2p);
  k_agg2  <<<N_NODES/4, 256, 0, stream>>>(offs, csrc, cea, as2p, ad2p, h2p, scal, b2, Wlin, outp);
}

// Round 5
// 309.241 us; speedup vs baseline: 2.2470x; 1.1757x over previous
//
#include <hip/hip_runtime.h>
#include <hip/hip_fp16.h>
#include <math.h>

#define N_NODES 50000
#define N_EDGES 800000
#define E2 (N_EDGES + N_NODES)   // 850000
#define HEADS 5
#define C1 32
#define F1 160

// counting-sort CSR build
#define NBK 391                  // buckets of 128 nodes
#define NBL 416                  // edge-chunk blocks
#define CH  2044                 // 416*2044 >= E2
#define MTOT (NBK*NBL)           // 162656
#define MC  636                  // ceil(MTOT/256)

static constexpr size_t alignup(size_t x){ return (x + 255) & ~size_t(255); }
static constexpr size_t OFF_SCAL  = 0;                                           // 64 f
static constexpr size_t OFF_H     = alignup(OFF_SCAL + 64*4);                    // MTOT i
static constexpr size_t OFF_PART  = alignup(OFF_H    + (size_t)MTOT*4);
static constexpr size_t OFF_PPREF = alignup(OFF_PART + (size_t)MC*4);
static constexpr size_t OFF_BST   = alignup(OFF_PPREF+ (size_t)MC*4);            // NBK+1
static constexpr size_t OFF_OFFS  = alignup(OFF_BST  + (size_t)(NBK+1)*4);       // N+1
static constexpr size_t OFF_BPACK = alignup(OFF_OFFS + (size_t)(N_NODES+1)*4);   // E2 int2
static constexpr size_t OFF_CSRC  = alignup(OFF_BPACK+ (size_t)E2*8);            // E2 i
static constexpr size_t OFF_CEA   = alignup(OFF_CSRC + (size_t)E2*4);            // E2 f
static constexpr size_t OFF_AS1P  = alignup(OFF_CEA  + (size_t)E2*4);            // N*8 f
static constexpr size_t OFF_AD1P  = alignup(OFF_AS1P + (size_t)N_NODES*8*4);
static constexpr size_t OFF_IDEN1 = alignup(OFF_AD1P + (size_t)N_NODES*8*4);
static constexpr size_t OFF_H2P   = alignup(OFF_IDEN1+ (size_t)N_NODES*8*4);
static constexpr size_t OFF_AS2P  = alignup(OFF_H2P  + (size_t)N_NODES*8*4);
static constexpr size_t OFF_AD2P  = alignup(OFF_AS2P + (size_t)N_NODES*8*4);
static constexpr size_t OFF_H1H   = alignup(OFF_AD2P + (size_t)N_NODES*8*4);     // N*160 half
static constexpr size_t OFF_X2H   = alignup(OFF_H1H  + (size_t)N_NODES*F1*2);    // N*160 half
static constexpr size_t OFF_ALPH  = alignup(OFF_X2H  + (size_t)N_NODES*F1*2);    // 5*E2 f

// ---- pass 1: LDS coarse histogram + ea sum ----
__global__ __launch_bounds__(256) void k_hist(const int* __restrict__ dst, const float* __restrict__ ea,
                       int* __restrict__ H, float* __restrict__ scal){
  __shared__ int hist[NBK];
  for (int k = threadIdx.x; k < NBK; k += 256) hist[k] = 0;
  __syncthreads();
  int b = blockIdx.x;
  int e0 = b*CH, e1 = min(e0 + CH, E2);
  float s = 0.f;
  for (int e = e0 + threadIdx.x; e < e1; e += 256){
    int d;
    if (e < N_EDGES){ d = dst[e]; s += ea[e]; }
    else d = e - N_EDGES;
    atomicAdd(&hist[d >> 7], 1);
  }
  __syncthreads();
  for (int k = threadIdx.x; k < NBK; k += 256) H[(size_t)k*NBL + b] = hist[k];
  #pragma unroll
  for (int m = 1; m < 64; m <<= 1) s += __shfl_xor(s, m, 64);
  if ((threadIdx.x & 63) == 0) atomicAdd(scal, s);
}

// scal[0]=sum_ea, scal[1]=mean_ea, scal[2..6]=wedot1[h], scal[7..11]=wedot2[h]
__global__ void k_prep(const float* __restrict__ We1, const float* __restrict__ ae1,
                       const float* __restrict__ We2, const float* __restrict__ ae2,
                       float* __restrict__ scal){
  int t = threadIdx.x;
  if (t == 0) scal[1] = scal[0] / (float)N_EDGES;
  if (t < HEADS){
    float s = 0.f;
    for (int c = 0; c < C1; c++) s += We1[t*C1 + c] * ae1[t*C1 + c];
    scal[2 + t] = s;
    scal[7 + t] = We2[t] * ae2[t];
  }
}

// ---- scan of H ----
__global__ void k_s1(const int* __restrict__ H, int* __restrict__ partial){
  int i = blockIdx.x*256 + threadIdx.x;
  int v = (i < MTOT) ? H[i] : 0;
  #pragma unroll
  for (int m = 1; m < 64; m <<= 1) v += __shfl_xor(v, m, 64);
  __shared__ int sh[4];
  if ((threadIdx.x & 63) == 0) sh[threadIdx.x >> 6] = v;
  __syncthreads();
  if (threadIdx.x == 0) partial[blockIdx.x] = sh[0] + sh[1] + sh[2] + sh[3];
}

__global__ __launch_bounds__(1024) void k_s2(const int* __restrict__ partial, int* __restrict__ ppref,
                      int* __restrict__ offs, int* __restrict__ bstart){
  __shared__ int sp[1024];
  int t = threadIdx.x;
  int v = (t < MC) ? partial[t] : 0;
  sp[t] = v;
  __syncthreads();
  for (int off = 1; off < 1024; off <<= 1){
    int u = (t >= off) ? sp[t - off] : 0;
    __syncthreads();
    sp[t] += u;
    __syncthreads();
  }
  if (t < MC) ppref[t] = sp[t] - v;
  if (t == 0){ offs[N_NODES] = E2; bstart[NBK] = E2; }
}

__global__ void k_s3(int* __restrict__ H, const int* __restrict__ ppref, int* __restrict__ bstart){
  __shared__ int sp[256];
  int b = blockIdx.x, t = threadIdx.x;
  int i = b*256 + t;
  int v = (i < MTOT) ? H[i] : 0;
  sp[t] = v;
  __syncthreads();
  for (int off = 1; off < 256; off <<= 1){
    int u = (t >= off) ? sp[t - off] : 0;
    __syncthreads();
    sp[t] += u;
    __syncthreads();
  }
  int P = ppref[b] + sp[t] - v;
  if (i < MTOT){
    H[i] = P;
    if (i % NBL == 0) bstart[i / NBL] = P;
  }
}

// ---- pass 2: scatter into bucket-major packed intermediate (8B/edge) ----
__global__ __launch_bounds__(256) void k_scat(const int* __restrict__ src, const int* __restrict__ dst,
                       const float* __restrict__ ea, const float* __restrict__ scal,
                       const int* __restrict__ H, int2* __restrict__ bpack){
  __shared__ int lofs[NBK];
  int b = blockIdx.x;
  for (int k = threadIdx.x; k < NBK; k += 256) lofs[k] = H[(size_t)k*NBL + b];
  __syncthreads();
  float mean = scal[1];
  int e0 = b*CH, e1 = min(e0 + CH, E2);
  for (int e = e0 + threadIdx.x; e < e1; e += 256){
    int d, s; float a;
    if (e < N_EDGES){ d = dst[e]; s = src[e]; a = ea[e]; }
    else { d = s = e - N_EDGES; a = mean; }
    int pos = atomicAdd(&lofs[d >> 7], 1);
    bpack[pos] = make_int2(s | ((d & 127) << 16), __float_as_int(a));
  }
}

// ---- pass 3: per-bucket fine sort ----
__global__ __launch_bounds__(256) void k_final(const int* __restrict__ bstart,
                        const int2* __restrict__ bpack,
                        int* __restrict__ offs, int* __restrict__ csrc, float* __restrict__ cea){
  int k = blockIdx.x, t = threadIdx.x;
  int r0 = bstart[k], r1 = bstart[k + 1];
  __shared__ int cnt[128], pfx[128], cur[128];
  if (t < 128) cnt[t] = 0;
  __syncthreads();
  for (int j = r0 + t; j < r1; j += 256) atomicAdd(&cnt[bpack[j].x >> 16], 1);
  __syncthreads();
  if (t == 0){
    int run = 0;
    for (int i = 0; i < 128; i++){ pfx[i] = run; cur[i] = run; run += cnt[i]; }
  }
  __syncthreads();
  int n = k*128 + t;
  if (t < 128 && n < N_NODES) offs[n] = r0 + pfx[t];
  for (int j = r0 + t; j < r1; j += 256){
    int2 v = bpack[j];
    int pos = r0 + atomicAdd(&cur[v.x >> 16], 1);
    csrc[pos] = v.x & 0xFFFF;
    cea[pos]  = __int_as_float(v.y);
  }
}

// ---- layer 1: h1h(fp16) = x@W1, as1p/ad1p (padded 8) ----
__global__ __launch_bounds__(320) void k_h1(const float* __restrict__ x, const float* __restrict__ W1,
                    const float* __restrict__ as1w, const float* __restrict__ ad1w,
                    __half* __restrict__ h1h, float* __restrict__ as1p, float* __restrict__ ad1p){
  __shared__ float sW[5*F1];
  for (int k = threadIdx.x; k < 5*F1; k += 320) sW[k] = W1[k];
  __syncthreads();
  int nl = threadIdx.x / 80;
  int c  = threadIdx.x - nl*80;
  int n  = blockIdx.x*4 + nl;
  int c0 = 2*c;
  float hv0 = 0.f, hv1 = 0.f;
  #pragma unroll
  for (int f = 0; f < 5; f++){
    float xv = x[n*5 + f];
    hv0 += xv * sW[f*F1 + c0];
    hv1 += xv * sW[f*F1 + c0 + 1];
  }
  ((__half2*)h1h)[n*80 + c] = __floats2half2_rn(hv0, hv1);
  float vs = hv0*as1w[c0] + hv1*as1w[c0+1];
  float vd = hv0*ad1w[c0] + hv1*ad1w[c0+1];
  #pragma unroll
  for (int m = 8; m >= 1; m >>= 1){
    vs += __shfl_xor(vs, m, 64);
    vd += __shfl_xor(vd, m, 64);
  }
  if ((c & 15) == 0){
    int h = c >> 4;
    as1p[n*8 + h] = vs;
    ad1p[n*8 + h] = vd;
  }
}

// ---- layer 1 softmax stats (single sweep, no max-sub): alpha=exp(lg), 1/den ----
__global__ __launch_bounds__(256) void k_soft2(const int* __restrict__ offs, const int* __restrict__ csrc,
                        const float* __restrict__ cea,
                        const float* __restrict__ as1p, const float* __restrict__ ad1p,
                        const float* __restrict__ scal,
                        float* __restrict__ alpha, float* __restrict__ iden1){
  int w = threadIdx.x >> 6, l = threadIdx.x & 63;
  int n = blockIdx.x*4 + w;
  float wd[HEADS], adn[HEADS];
  #pragma unroll
  for (int h = 0; h < HEADS; h++){ wd[h] = scal[2 + h]; adn[h] = ad1p[n*8 + h]; }
  int j0 = offs[n], j1 = offs[n + 1];

  float den[HEADS] = {0,0,0,0,0};
  for (int j = j0 + l; j < j1; j += 64){
    int s = csrc[j];
    float c = cea[j];
    float4 g4 = *(const float4*)(as1p + s*8);
    float g5 = as1p[s*8 + 4];
    float g[HEADS] = {g4.x, g4.y, g4.z, g4.w, g5};
    #pragma unroll
    for (int h = 0; h < HEADS; h++){
      float lg = g[h] + adn[h] + c*wd[h];
      lg = fmaxf(lg, 0.2f*lg);
      lg = fminf(fmaxf(lg, -50.f), 50.f);
      float p = __expf(lg);
      den[h] += p;
      alpha[(size_t)h*E2 + j] = p;
    }
  }
  #pragma unroll
  for (int m = 1; m < 64; m <<= 1){
    #pragma unroll
    for (int h = 0; h < HEADS; h++) den[h] += __shfl_xor(den[h], m, 64);
  }
  if (l == 0){
    #pragma unroll
    for (int h = 0; h < HEADS; h++) iden1[n*8 + h] = 1.f / (den[h] + 1e-16f);
  }
}

// ---- layer 1 aggregate: pure FMA gather, unroll 8 -> x2h(fp16) ----
__global__ __launch_bounds__(320) void k_agg1(const int* __restrict__ offs, const int* __restrict__ csrc,
                      const float* __restrict__ alpha, const float* __restrict__ iden1,
                      const __half* __restrict__ h1h,
                      const float* __restrict__ b1, __half* __restrict__ x2h){
  int nl = threadIdx.x / 80;
  int c  = threadIdx.x - nl*80;
  int n  = blockIdx.x*4 + nl;
  int h  = c >> 4;
  const float* aph = alpha + (size_t)h*E2;
  const __half2* h12 = (const __half2*)h1h;
  int j0 = offs[n], j1 = offs[n + 1];
  float acc0 = 0.f, acc1 = 0.f;
  int j = j0;
  int jal = min(j1, (j0 + 3) & ~3);
  for (; j < jal; ++j){
    int s = csrc[j];
    float a = aph[j];
    float2 f = __half22float2(h12[(size_t)s*80 + c]);
    acc0 += a*f.x; acc1 += a*f.y;
  }
  for (; j + 7 < j1; j += 8){
    int4   sa = *(const int4*)(csrc + j);
    int4   sb = *(const int4*)(csrc + j + 4);
    float4 aa = *(const float4*)(aph + j);
    float4 ab = *(const float4*)(aph + j + 4);
    __half2 r0 = h12[(size_t)sa.x*80 + c];
    __half2 r1 = h12[(size_t)sa.y*80 + c];
    __half2 r2 = h12[(size_t)sa.z*80 + c];
    __half2 r3 = h12[(size_t)sa.w*80 + c];
    __half2 r4 = h12[(size_t)sb.x*80 + c];
    __half2 r5 = h12[(size_t)sb.y*80 + c];
    __half2 r6 = h12[(size_t)sb.z*80 + c];
    __half2 r7 = h12[(size_t)sb.w*80 + c];
    float2 f0 = __half22float2(r0), f1 = __half22float2(r1);
    float2 f2 = __half22float2(r2), f3 = __half22float2(r3);
    float2 f4 = __half22float2(r4), f5 = __half22float2(r5);
    float2 f6 = __half22float2(r6), f7 = __half22float2(r7);
    acc0 += aa.x*f0.x; acc1 += aa.x*f0.y;
    acc0 += aa.y*f1.x; acc1 += aa.y*f1.y;
    acc0 += aa.z*f2.x; acc1 += aa.z*f2.y;
    acc0 += aa.w*f3.x; acc1 += aa.w*f3.y;
    acc0 += ab.x*f4.x; acc1 += ab.x*f4.y;
    acc0 += ab.y*f5.x; acc1 += ab.y*f5.y;
    acc0 += ab.z*f6.x; acc1 += ab.z*f6.y;
    acc0 += ab.w*f7.x; acc1 += ab.w*f7.y;
  }
  for (; j + 3 < j1; j += 4){
    int4   ss = *(const int4*)(csrc + j);
    float4 aa = *(const float4*)(aph + j);
    float2 f0 = __half22float2(h12[(size_t)ss.x*80 + c]);
    float2 f1 = __half22float2(h12[(size_t)ss.y*80 + c]);
    float2 f2 = __half22float2(h12[(size_t)ss.z*80 + c]);
    float2 f3 = __half22float2(h12[(size_t)ss.w*80 + c]);
    acc0 += aa.x*f0.x; acc1 += aa.x*f0.y;
    acc0 += aa.y*f1.x; acc1 += aa.y*f1.y;
    acc0 += aa.z*f2.x; acc1 += aa.z*f2.y;
    acc0 += aa.w*f3.x; acc1 += aa.w*f3.y;
  }
  for (; j < j1; ++j){
    int s = csrc[j];
    float a = aph[j];
    float2 f = __half22float2(h12[(size_t)s*80 + c]);
    acc0 += a*f.x; acc1 += a*f.y;
  }
  float inv = iden1[n*8 + h];
  float v0 = acc0*inv + b1[2*c];
  float v1 = acc1*inv + b1[2*c + 1];
  v0 = (v0 > 0.f) ? v0 : 0.f;
  v1 = (v1 > 0.f) ? v1 : 0.f;
  ((__half2*)x2h)[n*80 + c] = __floats2half2_rn(v0, v1);
}

// ---- layer 2: h2 = x2h@W2, padded rows of 8 ----
__global__ __launch_bounds__(256) void k_h2(const __half* __restrict__ x2h, const float* __restrict__ W2,
                    const float* __restrict__ asw2, const float* __restrict__ adw2,
                    float* __restrict__ h2p, float* __restrict__ as2p, float* __restrict__ ad2p){
  __shared__ float sW[F1*HEADS];
  for (int k = threadIdx.x; k < F1*HEADS; k += 256) sW[k] = W2[k];
  __syncthreads();
  int w = threadIdx.x >> 6, l = threadIdx.x & 63;
  int n = blockIdx.x*4 + w;
  const __half2* x22 = (const __half2*)x2h;
  float acc[HEADS] = {0.f, 0.f, 0.f, 0.f, 0.f};
  for (int k2 = l; k2 < 80; k2 += 64){
    float2 f = __half22float2(x22[n*80 + k2]);
    #pragma unroll
    for (int h = 0; h < HEADS; h++)
      acc[h] += f.x * sW[(2*k2)*HEADS + h] + f.y * sW[(2*k2+1)*HEADS + h];
  }
  #pragma unroll
  for (int m = 1; m < 64; m <<= 1){
    #pragma unroll
    for (int h = 0; h < HEADS; h++) acc[h] += __shfl_xor(acc[h], m, 64);
  }
  if (l == 0){
    #pragma unroll
    for (int h = 0; h < HEADS; h++){
      h2p[n*8 + h]  = acc[h];
      as2p[n*8 + h] = acc[h] * asw2[h];
      ad2p[n*8 + h] = acc[h] * adw2[h];
    }
  }
}

// ---- layer 2: single-sweep softmax aggregate + mean + linear + sigmoid ----
__global__ __launch_bounds__(256) void k_agg2(const int* __restrict__ offs, const int* __restrict__ csrc,
                      const float* __restrict__ cea,
                      const float* __restrict__ as2p, const float* __restrict__ ad2p,
                      const float* __restrict__ h2p, const float* __restrict__ scal,
                      const float* __restrict__ b2, const float* __restrict__ Wlin,
                      float* __restrict__ out){
  int w = threadIdx.x >> 6, l = threadIdx.x & 63;
  int n = blockIdx.x*4 + w;
  float adn[HEADS], wd[HEADS];
  #pragma unroll
  for (int h = 0; h < HEADS; h++){ adn[h] = ad2p[n*8 + h]; wd[h] = scal[7 + h]; }
  int j0 = offs[n], j1 = offs[n + 1];

  float den[HEADS] = {0,0,0,0,0};
  float ac[HEADS]  = {0,0,0,0,0};
  for (int j = j0 + l; j < j1; j += 64){
    int s = csrc[j];
    float c = cea[j];
    float4 g4 = *(const float4*)(as2p + s*8);
    float g5 = as2p[s*8 + 4];
    float g[HEADS] = {g4.x, g4.y, g4.z, g4.w, g5};
    float4 h4 = *(const float4*)(h2p + s*8);
    float h5 = h2p[s*8 + 4];
    float hv[HEADS] = {h4.x, h4.y, h4.z, h4.w, h5};
    #pragma unroll
    for (int h = 0; h < HEADS; h++){
      float lg = g[h] + adn[h] + c*wd[h];
      lg = fmaxf(lg, 0.2f*lg);
      lg = fminf(fmaxf(lg, -50.f), 50.f);
      float p = __expf(lg);
      den[h] += p;
      ac[h]  += p * hv[h];
    }
  }
  #pragma unroll
  for (int m = 1; m < 64; m <<= 1){
    #pragma unroll
    for (int h = 0; h < HEADS; h++){
      den[h] += __shfl_xor(den[h], m, 64);
      ac[h]  += __shfl_xor(ac[h], m, 64);
    }
  }
  if (l == 0){
    float v = 0.f;
    #pragma unroll
    for (int h = 0; h < HEADS; h++) v += ac[h] / (den[h] + 1e-16f);
    v = v * (1.f/HEADS) + b2[0];
    v *= Wlin[0];
    out[n] = 1.f / (1.f + __expf(-v));
  }
}

extern "C" void kernel_launch(void* const* d_in, const int* in_sizes, int n_in,
                              void* d_out, int out_size, void* d_ws, size_t ws_size,
                              hipStream_t stream) {
  const float* x    = (const float*)d_in[0];
  const float* ea   = (const float*)d_in[1];
  const int*   src  = (const int*)d_in[2];
  const int*   dst  = (const int*)d_in[3];
  const float* W1   = (const float*)d_in[4];
  const float* as1w = (const float*)d_in[5];
  const float* ad1w = (const float*)d_in[6];
  const float* We1  = (const float*)d_in[7];
  const float* ae1  = (const float*)d_in[8];
  const float* b1   = (const float*)d_in[9];
  const float* W2   = (const float*)d_in[10];
  const float* as2w = (const float*)d_in[11];
  const float* ad2w = (const float*)d_in[12];
  const float* We2  = (const float*)d_in[13];
  const float* ae2  = (const float*)d_in[14];
  const float* b2   = (const float*)d_in[15];
  const float* Wlin = (const float*)d_in[16];

  char* ws = (char*)d_ws;
  float* scal   = (float*)(ws + OFF_SCAL);
  int*   H      = (int*)  (ws + OFF_H);
  int*   part   = (int*)  (ws + OFF_PART);
  int*   ppref  = (int*)  (ws + OFF_PPREF);
  int*   bstart = (int*)  (ws + OFF_BST);
  int*   offs   = (int*)  (ws + OFF_OFFS);
  int2*  bpack  = (int2*) (ws + OFF_BPACK);
  int*   csrc   = (int*)  (ws + OFF_CSRC);
  float* cea    = (float*)(ws + OFF_CEA);
  float* as1p   = (float*)(ws + OFF_AS1P);
  float* ad1p   = (float*)(ws + OFF_AD1P);
  float* iden1  = (float*)(ws + OFF_IDEN1);
  float* h2p    = (float*)(ws + OFF_H2P);
  float* as2p   = (float*)(ws + OFF_AS2P);
  float* ad2p   = (float*)(ws + OFF_AD2P);
  __half* h1h   = (__half*)(ws + OFF_H1H);
  __half* x2h   = (__half*)(ws + OFF_X2H);
  float* alpha  = (float*)(ws + OFF_ALPH);
  float* outp   = (float*)d_out;

  hipMemsetAsync(scal, 0, 64*sizeof(float), stream);

  k_hist  <<<NBL, 256, 0, stream>>>(dst, ea, H, scal);
  k_prep  <<<1, 64, 0, stream>>>(We1, ae1, We2, ae2, scal);
  k_s1    <<<MC, 256, 0, stream>>>(H, part);
  k_s2    <<<1, 1024, 0, stream>>>(part, ppref, offs, bstart);
  k_s3    <<<MC, 256, 0, stream>>>(H, ppref, bstart);
  k_scat  <<<NBL, 256, 0, stream>>>(src, dst, ea, scal, H, bpack);
  k_final <<<NBK, 256, 0, stream>>>(bstart, bpack, offs, csrc, cea);

  k_h1    <<<N_NODES/4, 320, 0, stream>>>(x, W1, as1w, ad1w, h1h, as1p, ad1p);
  k_soft2 <<<N_NODES/4, 256, 0, stream>>>(offs, csrc, cea, as1p, ad1p, scal, alpha, iden1);
  k_agg1  <<<N_NODES/4, 320, 0, stream>>>(offs, csrc, alpha, iden1, h1h, b1, x2h);

  k_h2    <<<N_NODES/4, 256, 0, stream>>>(x2h, W2, as2w, ad2w, h2p, as2p, ad2p);
  k_agg2  <<<N_NODES/4, 256, 0, stream>>>(offs, csrc, cea, as2p, ad2p, h2p, scal, b2, Wlin, outp);
}